// Round 6
// baseline (5854.309 us; speedup 1.0000x reference)
//
// Round 6 = round 4 resubmission (rounds 1/3/5 died to broker infra, not code).
// Semantics: inputs f32 (+ int32 edge_index), output f32, bf16 MFMA internally.
#include <hip/hip_runtime.h>
#include <hip/hip_bf16.h>

typedef __attribute__((ext_vector_type(8))) short bf16x8;
typedef __attribute__((ext_vector_type(4))) float f32x4;
typedef unsigned short u16;
typedef unsigned int u32;

#define D 128      // D_IN == D_H
#define DC 256     // concat dim

__device__ __forceinline__ float bf2f(u16 b) {
    u32 u = ((u32)b) << 16;
    return __uint_as_float(u);
}
__device__ __forceinline__ u16 f2bf(float f) {
    u32 u = __float_as_uint(f);
    u32 r = (u + 0x7fffu + ((u >> 16) & 1u)) >> 16;   // RNE
    return (u16)r;
}
__device__ __forceinline__ float sigmoidf_(float x) {
    float e = __builtin_amdgcn_exp2f(-1.4426950408889634f * x);
    return __builtin_amdgcn_rcpf(1.0f + e);
}
// load 8 consecutive f32 (32B, aligned) and convert to a bf16x8 MFMA fragment
__device__ __forceinline__ bf16x8 cvt8(const float* __restrict__ p) {
    f32x4 lo = *(const f32x4*)p;
    f32x4 hi = *(const f32x4*)(p + 4);
    union { bf16x8 v; u16 s[8]; } u;
#pragma unroll
    for (int i = 0; i < 4; i++) {
        u.s[i]     = f2bf(lo[i]);
        u.s[i + 4] = f2bf(hi[i]);
    }
    return u.v;
}

// Wt[n*K + k] = bf16(W[k*128 + n])   (all weights have 128 output cols)
__global__ void transpose_kernel(const float* __restrict__ W, u16* __restrict__ Wt, int K) {
    int g = blockIdx.x * 256 + threadIdx.x;
    if (g >= K * 128) return;
    int k = g >> 7, n = g & 127;
    Wt[n * K + k] = f2bf(W[g]);
}

// r = sigmoid(x@Wxr + bxr + h@Whr); z = sigmoid(x@Wxz + bxz + h@Whz)
// writes rh = r*h (bf16) and z (bf16)
__global__ __launch_bounds__(256) void gates_kernel(
    const float* __restrict__ x, const float* __restrict__ h,
    const u16* __restrict__ WxrT, const u16* __restrict__ WhrT,
    const u16* __restrict__ WxzT, const u16* __restrict__ WhzT,
    const float* __restrict__ bxr, const float* __restrict__ bxz,
    u16* __restrict__ rh, u16* __restrict__ zo, int N)
{
    const int wave = threadIdx.x >> 6;
    const int lane = threadIdx.x & 63;
    const int quad = lane >> 4;
    const int l15  = lane & 15;
    const int node0 = blockIdx.x * 64 + wave * 16;
    if (node0 >= N) return;

    int arow = node0 + l15; if (arow >= N) arow = N - 1;
    const float* xp = x + (size_t)arow * D + quad * 8;
    const float* hp = h + (size_t)arow * D + quad * 8;
    bf16x8 ax[4], ah[4];
#pragma unroll
    for (int c = 0; c < 4; c++) {
        ax[c] = cvt8(xp + c * 32);
        ah[c] = cvt8(hp + c * 32);
    }

#pragma unroll
    for (int nt = 0; nt < 8; nt++) {
        f32x4 accr = {0.f, 0.f, 0.f, 0.f}, accz = {0.f, 0.f, 0.f, 0.f};
        const u16* wrx = WxrT + (size_t)(nt * 16 + l15) * D + quad * 8;
        const u16* wrh = WhrT + (size_t)(nt * 16 + l15) * D + quad * 8;
        const u16* wzx = WxzT + (size_t)(nt * 16 + l15) * D + quad * 8;
        const u16* wzh = WhzT + (size_t)(nt * 16 + l15) * D + quad * 8;
#pragma unroll
        for (int c = 0; c < 4; c++) {
            bf16x8 b0 = *(const bf16x8*)(wrx + c * 32);
            bf16x8 b1 = *(const bf16x8*)(wrh + c * 32);
            bf16x8 b2 = *(const bf16x8*)(wzx + c * 32);
            bf16x8 b3 = *(const bf16x8*)(wzh + c * 32);
            accr = __builtin_amdgcn_mfma_f32_16x16x32_bf16(ax[c], b0, accr, 0, 0, 0);
            accr = __builtin_amdgcn_mfma_f32_16x16x32_bf16(ah[c], b1, accr, 0, 0, 0);
            accz = __builtin_amdgcn_mfma_f32_16x16x32_bf16(ax[c], b2, accz, 0, 0, 0);
            accz = __builtin_amdgcn_mfma_f32_16x16x32_bf16(ah[c], b3, accz, 0, 0, 0);
        }
        int dim = nt * 16 + l15;
        float br = bxr[dim];
        float bz = bxz[dim];
#pragma unroll
        for (int reg = 0; reg < 4; reg++) {
            int node = node0 + quad * 4 + reg;
            if (node < N) {
                float r  = sigmoidf_(accr[reg] + br);
                float zz = sigmoidf_(accz[reg] + bz);
                float hv = h[(size_t)node * D + dim];
                rh[(size_t)node * D + dim] = f2bf(r * hv);
                zo[(size_t)node * D + dim] = f2bf(zz);
            }
        }
    }
}

// agg[dst] += [x|rh][src]; cnt[dst] += 1     (32 threads per edge, 8 dims each)
__global__ __launch_bounds__(256) void scatter_kernel(
    const int* __restrict__ ei, const float* __restrict__ x, const u16* __restrict__ rh,
    float* __restrict__ agg, float* __restrict__ cnt, int E)
{
    long long g = (long long)blockIdx.x * 256 + threadIdx.x;
    int e = (int)(g >> 5);
    if (e >= E) return;
    int sub = (int)(g & 31);
    int src = ei[e];
    int dst = ei[(size_t)E + e];
    float v[8];
    if (sub < 16) {
        const float* p = x + (size_t)src * D + sub * 8;
        f32x4 lo = *(const f32x4*)p;
        f32x4 hi = *(const f32x4*)(p + 4);
#pragma unroll
        for (int i = 0; i < 4; i++) { v[i] = lo[i]; v[i + 4] = hi[i]; }
    } else {
        const u16* p = rh + (size_t)src * D + (sub - 16) * 8;
        bf16x8 b = *(const bf16x8*)p;
#pragma unroll
        for (int i = 0; i < 8; i++) v[i] = bf2f((u16)b[i]);
    }
    float* ap = agg + (size_t)dst * DC + sub * 8;
#pragma unroll
    for (int i = 0; i < 8; i++)
        unsafeAtomicAdd(ap + i, v[i]);
    if (sub == 0) unsafeAtomicAdd(cnt + dst, 1.0f);
}

// n = mean@Wl + bl + x@Wr[0:128] + rh@Wr[128:256];  out = (1-z)*n + z*h  (f32 out)
__global__ __launch_bounds__(256) void combine_kernel(
    const float* __restrict__ agg, const float* __restrict__ cnt,
    const float* __restrict__ x, const u16* __restrict__ rh,
    const float* __restrict__ h, const u16* __restrict__ z,
    const u16* __restrict__ WlT, const u16* __restrict__ WrT,
    const float* __restrict__ bl, float* __restrict__ out, int N)
{
    const int wave = threadIdx.x >> 6;
    const int lane = threadIdx.x & 63;
    const int quad = lane >> 4;
    const int l15  = lane & 15;
    const int node0 = blockIdx.x * 64 + wave * 16;
    if (node0 >= N) return;

    int arow = node0 + l15; if (arow >= N) arow = N - 1;
    float inv = __builtin_amdgcn_rcpf(fmaxf(cnt[arow], 1.0f));

    // mean A-frags (8 k-chunks of 32 over DC=256)
    bf16x8 am[8];
    const float* agp = agg + (size_t)arow * DC + quad * 8;
#pragma unroll
    for (int c = 0; c < 8; c++) {
        f32x4 lo = *(const f32x4*)(agp + c * 32);
        f32x4 hi = *(const f32x4*)(agp + c * 32 + 4);
        union { bf16x8 v; u16 s[8]; } u;
#pragma unroll
        for (int i = 0; i < 4; i++) {
            u.s[i]     = f2bf(lo[i] * inv);
            u.s[i + 4] = f2bf(hi[i] * inv);
        }
        am[c] = u.v;
    }
    const float* xp = x  + (size_t)arow * D + quad * 8;
    const u16* rhp  = rh + (size_t)arow * D + quad * 8;
    bf16x8 axf[4], arh[4];
#pragma unroll
    for (int c = 0; c < 4; c++) {
        axf[c] = cvt8(xp + c * 32);
        arh[c] = *(const bf16x8*)(rhp + c * 32);
    }

#pragma unroll
    for (int nt = 0; nt < 8; nt++) {
        f32x4 acc = {0.f, 0.f, 0.f, 0.f};
        const u16* wl = WlT + (size_t)(nt * 16 + l15) * DC + quad * 8;
#pragma unroll
        for (int c = 0; c < 8; c++)
            acc = __builtin_amdgcn_mfma_f32_16x16x32_bf16(am[c], *(const bf16x8*)(wl + c * 32), acc, 0, 0, 0);
        const u16* wr = WrT + (size_t)(nt * 16 + l15) * DC + quad * 8;
#pragma unroll
        for (int c = 0; c < 4; c++)
            acc = __builtin_amdgcn_mfma_f32_16x16x32_bf16(axf[c], *(const bf16x8*)(wr + c * 32), acc, 0, 0, 0);
#pragma unroll
        for (int c = 0; c < 4; c++)
            acc = __builtin_amdgcn_mfma_f32_16x16x32_bf16(arh[c], *(const bf16x8*)(wr + 128 + c * 32), acc, 0, 0, 0);

        int dim = nt * 16 + l15;
        float blv = bl[dim];
#pragma unroll
        for (int reg = 0; reg < 4; reg++) {
            int node = node0 + quad * 4 + reg;
            if (node < N) {
                float nv = acc[reg] + blv;
                float zz = bf2f(z[(size_t)node * D + dim]);
                float hv = h[(size_t)node * D + dim];
                out[(size_t)node * D + dim] = (1.0f - zz) * nv + zz * hv;
            }
        }
    }
}

extern "C" void kernel_launch(void* const* d_in, const int* in_sizes, int n_in,
                              void* d_out, int out_size, void* d_ws, size_t ws_size,
                              hipStream_t stream)
{
    const float* x   = (const float*)d_in[0];
    const int*   ei  = (const int*)d_in[1];
    const float* h   = (const float*)d_in[2];
    const float* Wxr = (const float*)d_in[3];
    const float* bxr = (const float*)d_in[4];
    const float* Whr = (const float*)d_in[5];
    const float* Wxz = (const float*)d_in[6];
    const float* bxz = (const float*)d_in[7];
    const float* Whz = (const float*)d_in[8];
    const float* Wl  = (const float*)d_in[9];
    const float* bl  = (const float*)d_in[10];
    const float* Wr  = (const float*)d_in[11];
    float* out = (float*)d_out;

    const int N = in_sizes[0] / D;
    const int E = in_sizes[1] / 2;
    if (N <= 0 || E <= 0) return;

    char* ws = (char*)d_ws;
    size_t off = 0;
    auto alloc = [&](size_t bytes) -> void* {
        void* p = ws + off;
        off += (bytes + 255) & ~(size_t)255;
        return p;
    };
    u16*   rh   = (u16*)  alloc((size_t)N * D * 2);
    u16*   z    = (u16*)  alloc((size_t)N * D * 2);
    float* agg  = (float*)alloc((size_t)N * DC * 4);
    float* cnt  = (float*)alloc((size_t)N * 4);
    u16*   WxrT = (u16*)  alloc((size_t)D * D * 2);
    u16*   WhrT = (u16*)  alloc((size_t)D * D * 2);
    u16*   WxzT = (u16*)  alloc((size_t)D * D * 2);
    u16*   WhzT = (u16*)  alloc((size_t)D * D * 2);
    u16*   WlT  = (u16*)  alloc((size_t)DC * D * 2);
    u16*   WrT  = (u16*)  alloc((size_t)DC * D * 2);
    (void)n_in; (void)out_size;

    // Defensive: if the workspace is smaller than required, do not launch
    // anything (clean validation failure instead of an OOB fault).
    if (off > ws_size) return;

    hipMemsetAsync(agg, 0, (size_t)N * DC * 4, stream);
    hipMemsetAsync(cnt, 0, (size_t)N * 4, stream);

    transpose_kernel<<<(D * D + 255) / 256, 256, 0, stream>>>(Wxr, WxrT, D);
    transpose_kernel<<<(D * D + 255) / 256, 256, 0, stream>>>(Whr, WhrT, D);
    transpose_kernel<<<(D * D + 255) / 256, 256, 0, stream>>>(Wxz, WxzT, D);
    transpose_kernel<<<(D * D + 255) / 256, 256, 0, stream>>>(Whz, WhzT, D);
    transpose_kernel<<<(DC * D + 255) / 256, 256, 0, stream>>>(Wl, WlT, DC);
    transpose_kernel<<<(DC * D + 255) / 256, 256, 0, stream>>>(Wr, WrT, DC);

    gates_kernel<<<(N + 63) / 64, 256, 0, stream>>>(
        x, h, WxrT, WhrT, WxzT, WhzT, bxr, bxz, rh, z, N);

    long long tot = (long long)E * 32;
    scatter_kernel<<<(int)((tot + 255) / 256), 256, 0, stream>>>(ei, x, rh, agg, cnt, E);

    combine_kernel<<<(N + 63) / 64, 256, 0, stream>>>(
        agg, cnt, x, rh, h, z, WlT, WrT, bl, out, N);
}

// Round 7
// 554.487 us; speedup vs baseline: 10.5581x; 10.5581x over previous
//
// Inputs f32 (+ int32 edge_index), output f32, bf16 MFMA internally.
// R7: replace atomic scatter (6.58 GB HBM writes, 5.6 ms) with CSR + pull-mode mean.
#include <hip/hip_runtime.h>
#include <hip/hip_bf16.h>

typedef __attribute__((ext_vector_type(8))) short bf16x8;
typedef __attribute__((ext_vector_type(4))) short bf16x4;
typedef __attribute__((ext_vector_type(4))) float f32x4;
typedef unsigned short u16;
typedef unsigned int u32;

#define D 128      // D_IN == D_H
#define DC 256     // concat dim

__device__ __forceinline__ float bf2f(u16 b) {
    u32 u = ((u32)b) << 16;
    return __uint_as_float(u);
}
__device__ __forceinline__ u16 f2bf(float f) {
    u32 u = __float_as_uint(f);
    u32 r = (u + 0x7fffu + ((u >> 16) & 1u)) >> 16;   // RNE
    return (u16)r;
}
__device__ __forceinline__ float sigmoidf_(float x) {
    float e = __builtin_amdgcn_exp2f(-1.4426950408889634f * x);
    return __builtin_amdgcn_rcpf(1.0f + e);
}
__device__ __forceinline__ bf16x8 cvt8(const float* __restrict__ p) {
    f32x4 lo = *(const f32x4*)p;
    f32x4 hi = *(const f32x4*)(p + 4);
    union { bf16x8 v; u16 s[8]; } u;
#pragma unroll
    for (int i = 0; i < 4; i++) {
        u.s[i]     = f2bf(lo[i]);
        u.s[i + 4] = f2bf(hi[i]);
    }
    return u.v;
}

// Wt[n*K + k] = bf16(W[k*128 + n])
__global__ void transpose_kernel(const float* __restrict__ W, u16* __restrict__ Wt, int K) {
    int g = blockIdx.x * 256 + threadIdx.x;
    if (g >= K * 128) return;
    int k = g >> 7, n = g & 127;
    Wt[n * K + k] = f2bf(W[g]);
}

// ---- CSR build ----
__global__ void hist_kernel(const int* __restrict__ ei, int* __restrict__ deg, int E) {
    int e = blockIdx.x * 256 + threadIdx.x;
    if (e < E) atomicAdd(&deg[ei[(size_t)E + e]], 1);
}

// single-block exclusive prefix sum over deg[0..N) -> row_start
__global__ __launch_bounds__(256) void scan_kernel(
    const int* __restrict__ deg, int* __restrict__ row_start, int N)
{
    __shared__ int part[256];
    int t = threadIdx.x;
    int chunk = (N + 255) / 256;
    int lo = t * chunk, hi = lo + chunk; if (hi > N) hi = N; if (lo > N) lo = N;
    int s = 0;
    for (int i = lo; i < hi; i++) s += deg[i];
    part[t] = s;
    __syncthreads();
    if (t == 0) {
        int run = 0;
        for (int i = 0; i < 256; i++) { int v = part[i]; part[i] = run; run += v; }
    }
    __syncthreads();
    int off = part[t];
    for (int i = lo; i < hi; i++) { row_start[i] = off; off += deg[i]; }
}

__global__ void fill_kernel(const int* __restrict__ ei, const int* __restrict__ row_start,
                            int* __restrict__ fillc, int* __restrict__ col, int E) {
    int e = blockIdx.x * 256 + threadIdx.x;
    if (e >= E) return;
    int src = ei[e], dst = ei[(size_t)E + e];
    int pos = atomicAdd(&fillc[dst], 1);
    col[row_start[dst] + pos] = src;
}

// ---- gates: r,z ; rh = r*h ----
__global__ __launch_bounds__(256) void gates_kernel(
    const float* __restrict__ x, const float* __restrict__ h,
    const u16* __restrict__ WxrT, const u16* __restrict__ WhrT,
    const u16* __restrict__ WxzT, const u16* __restrict__ WhzT,
    const float* __restrict__ bxr, const float* __restrict__ bxz,
    u16* __restrict__ rh, u16* __restrict__ zo, int N)
{
    const int wave = threadIdx.x >> 6;
    const int lane = threadIdx.x & 63;
    const int quad = lane >> 4;
    const int l15  = lane & 15;
    const int node0 = blockIdx.x * 64 + wave * 16;
    if (node0 >= N) return;

    int arow = node0 + l15; if (arow >= N) arow = N - 1;
    const float* xp = x + (size_t)arow * D + quad * 8;
    const float* hp = h + (size_t)arow * D + quad * 8;
    bf16x8 ax[4], ah[4];
#pragma unroll
    for (int c = 0; c < 4; c++) {
        ax[c] = cvt8(xp + c * 32);
        ah[c] = cvt8(hp + c * 32);
    }

#pragma unroll
    for (int nt = 0; nt < 8; nt++) {
        f32x4 accr = {0.f, 0.f, 0.f, 0.f}, accz = {0.f, 0.f, 0.f, 0.f};
        const u16* wrx = WxrT + (size_t)(nt * 16 + l15) * D + quad * 8;
        const u16* wrh = WhrT + (size_t)(nt * 16 + l15) * D + quad * 8;
        const u16* wzx = WxzT + (size_t)(nt * 16 + l15) * D + quad * 8;
        const u16* wzh = WhzT + (size_t)(nt * 16 + l15) * D + quad * 8;
#pragma unroll
        for (int c = 0; c < 4; c++) {
            bf16x8 b0 = *(const bf16x8*)(wrx + c * 32);
            bf16x8 b1 = *(const bf16x8*)(wrh + c * 32);
            bf16x8 b2 = *(const bf16x8*)(wzx + c * 32);
            bf16x8 b3 = *(const bf16x8*)(wzh + c * 32);
            accr = __builtin_amdgcn_mfma_f32_16x16x32_bf16(ax[c], b0, accr, 0, 0, 0);
            accr = __builtin_amdgcn_mfma_f32_16x16x32_bf16(ah[c], b1, accr, 0, 0, 0);
            accz = __builtin_amdgcn_mfma_f32_16x16x32_bf16(ax[c], b2, accz, 0, 0, 0);
            accz = __builtin_amdgcn_mfma_f32_16x16x32_bf16(ah[c], b3, accz, 0, 0, 0);
        }
        int dim = nt * 16 + l15;
        float br = bxr[dim];
        float bz = bxz[dim];
#pragma unroll
        for (int reg = 0; reg < 4; reg++) {
            int node = node0 + quad * 4 + reg;
            if (node < N) {
                float r  = sigmoidf_(accr[reg] + br);
                float zz = sigmoidf_(accz[reg] + bz);
                float hv = h[(size_t)node * D + dim];
                rh[(size_t)node * D + dim] = f2bf(r * hv);
                zo[(size_t)node * D + dim] = f2bf(zz);
            }
        }
    }
}

// ---- pull-mode mean aggregation: one wave per dst node ----
// lanes 0..31: x-part, 4 f32 dims each; lanes 32..63: rh-part, 4 bf16 dims each.
__global__ __launch_bounds__(256) void pull_kernel(
    const int* __restrict__ row_start, const int* __restrict__ deg,
    const int* __restrict__ col, const float* __restrict__ x,
    const u16* __restrict__ rh, u16* __restrict__ mean, int N)
{
    const int wave = threadIdx.x >> 6;
    const int lane = threadIdx.x & 63;
    const int node = blockIdx.x * 4 + wave;
    if (node >= N) return;

    const int base = row_start[node];
    const int d    = deg[node];
    const bool isx = lane < 32;
    const int  sl  = isx ? lane : lane - 32;

    float a0 = 0.f, a1 = 0.f, a2 = 0.f, a3 = 0.f;
    for (int i = 0; i < d; i++) {
        int s = col[base + i];
        if (isx) {
            f32x4 v = *(const f32x4*)(x + (size_t)s * D + sl * 4);
            a0 += v[0]; a1 += v[1]; a2 += v[2]; a3 += v[3];
        } else {
            bf16x4 v = *(const bf16x4*)(rh + (size_t)s * D + sl * 4);
            a0 += bf2f((u16)v[0]); a1 += bf2f((u16)v[1]);
            a2 += bf2f((u16)v[2]); a3 += bf2f((u16)v[3]);
        }
    }
    float inv = 1.0f / (float)(d > 0 ? d : 1);
    union { bf16x4 v; u16 s[4]; } o;
    o.s[0] = f2bf(a0 * inv); o.s[1] = f2bf(a1 * inv);
    o.s[2] = f2bf(a2 * inv); o.s[3] = f2bf(a3 * inv);
    int dimbase = (isx ? 0 : 128) + sl * 4;
    *(bf16x4*)(mean + (size_t)node * DC + dimbase) = o.v;
}

// n = mean@Wl + bl + x@Wr[0:128] + rh@Wr[128:256];  out = (1-z)*n + z*h  (f32 out)
__global__ __launch_bounds__(256) void combine_kernel(
    const u16* __restrict__ mean,
    const float* __restrict__ x, const u16* __restrict__ rh,
    const float* __restrict__ h, const u16* __restrict__ z,
    const u16* __restrict__ WlT, const u16* __restrict__ WrT,
    const float* __restrict__ bl, float* __restrict__ out, int N)
{
    const int wave = threadIdx.x >> 6;
    const int lane = threadIdx.x & 63;
    const int quad = lane >> 4;
    const int l15  = lane & 15;
    const int node0 = blockIdx.x * 64 + wave * 16;
    if (node0 >= N) return;

    int arow = node0 + l15; if (arow >= N) arow = N - 1;

    bf16x8 am[8];
    const u16* mp = mean + (size_t)arow * DC + quad * 8;
#pragma unroll
    for (int c = 0; c < 8; c++)
        am[c] = *(const bf16x8*)(mp + c * 32);

    const float* xp = x  + (size_t)arow * D + quad * 8;
    const u16* rhp  = rh + (size_t)arow * D + quad * 8;
    bf16x8 axf[4], arh[4];
#pragma unroll
    for (int c = 0; c < 4; c++) {
        axf[c] = cvt8(xp + c * 32);
        arh[c] = *(const bf16x8*)(rhp + c * 32);
    }

#pragma unroll
    for (int nt = 0; nt < 8; nt++) {
        f32x4 acc = {0.f, 0.f, 0.f, 0.f};
        const u16* wl = WlT + (size_t)(nt * 16 + l15) * DC + quad * 8;
#pragma unroll
        for (int c = 0; c < 8; c++)
            acc = __builtin_amdgcn_mfma_f32_16x16x32_bf16(am[c], *(const bf16x8*)(wl + c * 32), acc, 0, 0, 0);
        const u16* wr = WrT + (size_t)(nt * 16 + l15) * DC + quad * 8;
#pragma unroll
        for (int c = 0; c < 4; c++)
            acc = __builtin_amdgcn_mfma_f32_16x16x32_bf16(axf[c], *(const bf16x8*)(wr + c * 32), acc, 0, 0, 0);
#pragma unroll
        for (int c = 0; c < 4; c++)
            acc = __builtin_amdgcn_mfma_f32_16x16x32_bf16(arh[c], *(const bf16x8*)(wr + 128 + c * 32), acc, 0, 0, 0);

        int dim = nt * 16 + l15;
        float blv = bl[dim];
#pragma unroll
        for (int reg = 0; reg < 4; reg++) {
            int node = node0 + quad * 4 + reg;
            if (node < N) {
                float nv = acc[reg] + blv;
                float zz = bf2f(z[(size_t)node * D + dim]);
                float hv = h[(size_t)node * D + dim];
                out[(size_t)node * D + dim] = (1.0f - zz) * nv + zz * hv;
            }
        }
    }
}

extern "C" void kernel_launch(void* const* d_in, const int* in_sizes, int n_in,
                              void* d_out, int out_size, void* d_ws, size_t ws_size,
                              hipStream_t stream)
{
    const float* x   = (const float*)d_in[0];
    const int*   ei  = (const int*)d_in[1];
    const float* h   = (const float*)d_in[2];
    const float* Wxr = (const float*)d_in[3];
    const float* bxr = (const float*)d_in[4];
    const float* Whr = (const float*)d_in[5];
    const float* Wxz = (const float*)d_in[6];
    const float* bxz = (const float*)d_in[7];
    const float* Whz = (const float*)d_in[8];
    const float* Wl  = (const float*)d_in[9];
    const float* bl  = (const float*)d_in[10];
    const float* Wr  = (const float*)d_in[11];
    float* out = (float*)d_out;

    const int N = in_sizes[0] / D;
    const int E = in_sizes[1] / 2;
    if (N <= 0 || E <= 0) return;

    char* ws = (char*)d_ws;
    size_t off = 0;
    auto alloc = [&](size_t bytes) -> void* {
        void* p = ws + off;
        off += (bytes + 255) & ~(size_t)255;
        return p;
    };
    u16*   rh    = (u16*)  alloc((size_t)N * D * 2);
    u16*   z     = (u16*)  alloc((size_t)N * D * 2);
    u16*   mean  = (u16*)  alloc((size_t)N * DC * 2);
    int*   deg   = (int*)  alloc((size_t)N * 4);
    int*   rstart= (int*)  alloc((size_t)N * 4);
    int*   fillc = (int*)  alloc((size_t)N * 4);
    int*   col   = (int*)  alloc((size_t)E * 4);
    u16*   WxrT  = (u16*)  alloc((size_t)D * D * 2);
    u16*   WhrT  = (u16*)  alloc((size_t)D * D * 2);
    u16*   WxzT  = (u16*)  alloc((size_t)D * D * 2);
    u16*   WhzT  = (u16*)  alloc((size_t)D * D * 2);
    u16*   WlT   = (u16*)  alloc((size_t)DC * D * 2);
    u16*   WrT   = (u16*)  alloc((size_t)DC * D * 2);
    (void)n_in; (void)out_size;
    if (off > ws_size) return;   // clean failure instead of OOB fault

    hipMemsetAsync(deg,   0, (size_t)N * 4, stream);
    hipMemsetAsync(fillc, 0, (size_t)N * 4, stream);

    transpose_kernel<<<(D * D + 255) / 256, 256, 0, stream>>>(Wxr, WxrT, D);
    transpose_kernel<<<(D * D + 255) / 256, 256, 0, stream>>>(Whr, WhrT, D);
    transpose_kernel<<<(D * D + 255) / 256, 256, 0, stream>>>(Wxz, WxzT, D);
    transpose_kernel<<<(D * D + 255) / 256, 256, 0, stream>>>(Whz, WhzT, D);
    transpose_kernel<<<(DC * D + 255) / 256, 256, 0, stream>>>(Wl, WlT, DC);
    transpose_kernel<<<(DC * D + 255) / 256, 256, 0, stream>>>(Wr, WrT, DC);

    hist_kernel<<<(E + 255) / 256, 256, 0, stream>>>(ei, deg, E);
    scan_kernel<<<1, 256, 0, stream>>>(deg, rstart, N);
    fill_kernel<<<(E + 255) / 256, 256, 0, stream>>>(ei, rstart, fillc, col, E);

    gates_kernel<<<(N + 63) / 64, 256, 0, stream>>>(
        x, h, WxrT, WhrT, WxzT, WhzT, bxr, bxz, rh, z, N);

    pull_kernel<<<(N + 3) / 4, 256, 0, stream>>>(rstart, deg, col, x, rh, mean, N);

    combine_kernel<<<(N + 63) / 64, 256, 0, stream>>>(
        mean, x, rh, h, z, WlT, WrT, bl, out, N);
}

// Round 8
// 494.195 us; speedup vs baseline: 11.8462x; 1.1220x over previous
//
// Inputs f32 (+ int32 edge_index), output f32, bf16 MFMA internally.
// R8: aggregate AFTER projecting (mean∘linear commute): y=[x|rh]@Wl per node,
// pull gathers 256B y-rows (was 768B x|rh) -> 3x less gather traffic.
#include <hip/hip_runtime.h>
#include <hip/hip_bf16.h>

typedef __attribute__((ext_vector_type(8))) short bf16x8;
typedef __attribute__((ext_vector_type(4))) float f32x4;
typedef unsigned short u16;
typedef unsigned int u32;

#define D 128      // D_IN == D_H
#define DC 256     // concat dim

__device__ __forceinline__ float bf2f(u16 b) {
    u32 u = ((u32)b) << 16;
    return __uint_as_float(u);
}
__device__ __forceinline__ u16 f2bf(float f) {
    u32 u = __float_as_uint(f);
    u32 r = (u + 0x7fffu + ((u >> 16) & 1u)) >> 16;   // RNE
    return (u16)r;
}
__device__ __forceinline__ float sigmoidf_(float x) {
    float e = __builtin_amdgcn_exp2f(-1.4426950408889634f * x);
    return __builtin_amdgcn_rcpf(1.0f + e);
}
__device__ __forceinline__ bf16x8 cvt8(const float* __restrict__ p) {
    f32x4 lo = *(const f32x4*)p;
    f32x4 hi = *(const f32x4*)(p + 4);
    union { bf16x8 v; u16 s[8]; } u;
#pragma unroll
    for (int i = 0; i < 4; i++) {
        u.s[i]     = f2bf(lo[i]);
        u.s[i + 4] = f2bf(hi[i]);
    }
    return u.v;
}

// Fused prep: 6 weight transposes (f32->bf16) + xb=bf16(x) + degree histogram.
// Block ranges: [0,64)x4 gate weights, [256,384) Wl, [384,512) Wr,
// [512,512+nbx) xcast, [512+nbx, ...) hist.
__global__ __launch_bounds__(256) void prep_kernel(
    const float* __restrict__ Wxr, const float* __restrict__ Whr,
    const float* __restrict__ Wxz, const float* __restrict__ Whz,
    const float* __restrict__ Wl,  const float* __restrict__ Wr,
    u16* __restrict__ WxrT, u16* __restrict__ WhrT,
    u16* __restrict__ WxzT, u16* __restrict__ WhzT,
    u16* __restrict__ WlT,  u16* __restrict__ WrT,
    const float* __restrict__ x, u16* __restrict__ xb,
    const int* __restrict__ ei, int* __restrict__ deg,
    int N, int E, int nbx)
{
    int bid = blockIdx.x;
    int tid = threadIdx.x;
    if (bid < 256) {                       // 4 gate weights, 128x128 each
        int m = bid >> 6;                  // which matrix
        int g = (bid & 63) * 256 + tid;    // elem in [0,16384)
        const float* W = (m == 0) ? Wxr : (m == 1) ? Whr : (m == 2) ? Wxz : Whz;
        u16* Wt        = (m == 0) ? WxrT : (m == 1) ? WhrT : (m == 2) ? WxzT : WhzT;
        int k = g >> 7, n = g & 127;
        Wt[n * D + k] = f2bf(W[g]);
    } else if (bid < 512) {                // Wl / Wr, 256x128 each
        int m = (bid - 256) >> 7;
        int g = ((bid - 256) & 127) * 256 + tid;   // elem in [0,32768)
        const float* W = (m == 0) ? Wl : Wr;
        u16* Wt        = (m == 0) ? WlT : WrT;
        int k = g >> 7, n = g & 127;
        Wt[n * DC + k] = f2bf(W[g]);
    } else if (bid < 512 + nbx) {          // xb = bf16(x)
        long long g = (long long)(bid - 512) * 256 + tid;
        if (g < (long long)N * D) xb[g] = f2bf(x[g]);
    } else {                               // histogram of dst
        long long e = (long long)(bid - 512 - nbx) * 256 + tid;
        if (e < E) atomicAdd(&deg[ei[(size_t)E + e]], 1);
    }
}

// single-block exclusive prefix sum deg -> row_start; also zeroes fillc
__global__ __launch_bounds__(256) void scan_kernel(
    const int* __restrict__ deg, int* __restrict__ row_start,
    int* __restrict__ fillc, int N)
{
    __shared__ int part[256];
    int t = threadIdx.x;
    int chunk = (N + 255) / 256;
    int lo = t * chunk, hi = lo + chunk; if (hi > N) hi = N; if (lo > N) lo = N;
    int s = 0;
    for (int i = lo; i < hi; i++) s += deg[i];
    part[t] = s;
    __syncthreads();
    if (t == 0) {
        int run = 0;
        for (int i = 0; i < 256; i++) { int v = part[i]; part[i] = run; run += v; }
    }
    __syncthreads();
    int off = part[t];
    for (int i = lo; i < hi; i++) { row_start[i] = off; off += deg[i]; fillc[i] = 0; }
}

__global__ void fill_kernel(const int* __restrict__ ei, const int* __restrict__ row_start,
                            int* __restrict__ fillc, int* __restrict__ col, int E) {
    int e = blockIdx.x * 256 + threadIdx.x;
    if (e >= E) return;
    int src = ei[e], dst = ei[(size_t)E + e];
    int pos = atomicAdd(&fillc[dst], 1);
    col[row_start[dst] + pos] = src;
}

// ---- gates: r,z ; rh = r*h ----
__global__ __launch_bounds__(256) void gates_kernel(
    const u16* __restrict__ xb, const float* __restrict__ h,
    const u16* __restrict__ WxrT, const u16* __restrict__ WhrT,
    const u16* __restrict__ WxzT, const u16* __restrict__ WhzT,
    const float* __restrict__ bxr, const float* __restrict__ bxz,
    u16* __restrict__ rh, u16* __restrict__ zo, int N)
{
    const int wave = threadIdx.x >> 6;
    const int lane = threadIdx.x & 63;
    const int quad = lane >> 4;
    const int l15  = lane & 15;
    const int node0 = blockIdx.x * 64 + wave * 16;
    if (node0 >= N) return;

    int arow = node0 + l15; if (arow >= N) arow = N - 1;
    const u16*   xp = xb + (size_t)arow * D + quad * 8;
    const float* hp = h  + (size_t)arow * D + quad * 8;
    bf16x8 ax[4], ah[4];
#pragma unroll
    for (int c = 0; c < 4; c++) {
        ax[c] = *(const bf16x8*)(xp + c * 32);
        ah[c] = cvt8(hp + c * 32);
    }

#pragma unroll
    for (int nt = 0; nt < 8; nt++) {
        f32x4 accr = {0.f, 0.f, 0.f, 0.f}, accz = {0.f, 0.f, 0.f, 0.f};
        const u16* wrx = WxrT + (size_t)(nt * 16 + l15) * D + quad * 8;
        const u16* wrh = WhrT + (size_t)(nt * 16 + l15) * D + quad * 8;
        const u16* wzx = WxzT + (size_t)(nt * 16 + l15) * D + quad * 8;
        const u16* wzh = WhzT + (size_t)(nt * 16 + l15) * D + quad * 8;
#pragma unroll
        for (int c = 0; c < 4; c++) {
            bf16x8 b0 = *(const bf16x8*)(wrx + c * 32);
            bf16x8 b1 = *(const bf16x8*)(wrh + c * 32);
            bf16x8 b2 = *(const bf16x8*)(wzx + c * 32);
            bf16x8 b3 = *(const bf16x8*)(wzh + c * 32);
            accr = __builtin_amdgcn_mfma_f32_16x16x32_bf16(ax[c], b0, accr, 0, 0, 0);
            accr = __builtin_amdgcn_mfma_f32_16x16x32_bf16(ah[c], b1, accr, 0, 0, 0);
            accz = __builtin_amdgcn_mfma_f32_16x16x32_bf16(ax[c], b2, accz, 0, 0, 0);
            accz = __builtin_amdgcn_mfma_f32_16x16x32_bf16(ah[c], b3, accz, 0, 0, 0);
        }
        int dim = nt * 16 + l15;
        float br = bxr[dim];
        float bz = bxz[dim];
#pragma unroll
        for (int reg = 0; reg < 4; reg++) {
            int node = node0 + quad * 4 + reg;
            if (node < N) {
                float r  = sigmoidf_(accr[reg] + br);
                float zz = sigmoidf_(accz[reg] + bz);
                float hv = h[(size_t)node * D + dim];
                rh[(size_t)node * D + dim] = f2bf(r * hv);
                zo[(size_t)node * D + dim] = f2bf(zz);
            }
        }
    }
}

// ---- proj: y = [xb | rh] @ Wl   (per node, K=256, bf16 out) ----
__global__ __launch_bounds__(256) void proj_kernel(
    const u16* __restrict__ xb, const u16* __restrict__ rh,
    const u16* __restrict__ WlT, u16* __restrict__ y, int N)
{
    const int wave = threadIdx.x >> 6;
    const int lane = threadIdx.x & 63;
    const int quad = lane >> 4;
    const int l15  = lane & 15;
    const int node0 = blockIdx.x * 64 + wave * 16;
    if (node0 >= N) return;

    int arow = node0 + l15; if (arow >= N) arow = N - 1;
    const u16* xp  = xb + (size_t)arow * D + quad * 8;
    const u16* rhp = rh + (size_t)arow * D + quad * 8;
    bf16x8 axf[4], arh[4];
#pragma unroll
    for (int c = 0; c < 4; c++) {
        axf[c] = *(const bf16x8*)(xp + c * 32);
        arh[c] = *(const bf16x8*)(rhp + c * 32);
    }

#pragma unroll
    for (int nt = 0; nt < 8; nt++) {
        f32x4 acc = {0.f, 0.f, 0.f, 0.f};
        const u16* wl = WlT + (size_t)(nt * 16 + l15) * DC + quad * 8;
#pragma unroll
        for (int c = 0; c < 4; c++)
            acc = __builtin_amdgcn_mfma_f32_16x16x32_bf16(axf[c], *(const bf16x8*)(wl + c * 32), acc, 0, 0, 0);
#pragma unroll
        for (int c = 0; c < 4; c++)
            acc = __builtin_amdgcn_mfma_f32_16x16x32_bf16(arh[c], *(const bf16x8*)(wl + 128 + c * 32), acc, 0, 0, 0);

        int dim = nt * 16 + l15;
#pragma unroll
        for (int reg = 0; reg < 4; reg++) {
            int node = node0 + quad * 4 + reg;
            if (node < N)
                y[(size_t)node * D + dim] = f2bf(acc[reg]);
        }
    }
}

// ---- pull: meanY[n] = mean over edges of y[src]  (1 wave/node, 4 edges/iter) ----
__global__ __launch_bounds__(256) void pull_kernel(
    const int* __restrict__ row_start, const int* __restrict__ deg,
    const int* __restrict__ col, const u16* __restrict__ y,
    float* __restrict__ meanY, int N)
{
    const int wave = threadIdx.x >> 6;
    const int lane = threadIdx.x & 63;
    const int node = blockIdx.x * 4 + wave;
    if (node >= N) return;

    const int base = row_start[node];
    const int d    = deg[node];
    const int g    = lane >> 4;       // edge sub-group 0..3
    const int l15  = lane & 15;       // 16B segment of the y row

    float a[8] = {0.f,0.f,0.f,0.f,0.f,0.f,0.f,0.f};
    for (int i = 0; i < d; i += 4) {
        int e = i + g;
        if (e < d) {
            int s = col[base + e];
            bf16x8 v = *(const bf16x8*)(y + (size_t)s * D + l15 * 8);
#pragma unroll
            for (int j = 0; j < 8; j++) a[j] += bf2f((u16)v[j]);
        }
    }
#pragma unroll
    for (int j = 0; j < 8; j++) {
        a[j] += __shfl_xor(a[j], 16, 64);
        a[j] += __shfl_xor(a[j], 32, 64);
    }
    if (lane < 16) {
        float inv = 1.0f / (float)(d > 0 ? d : 1);
        f32x4 o0 = {a[0]*inv, a[1]*inv, a[2]*inv, a[3]*inv};
        f32x4 o1 = {a[4]*inv, a[5]*inv, a[6]*inv, a[7]*inv};
        float* mp = meanY + (size_t)node * D + l15 * 8;
        *(f32x4*)mp       = o0;
        *(f32x4*)(mp + 4) = o1;
    }
}

// n = meanY + bl + [xb|rh]@Wr;  out = (1-z)*n + z*h  (f32 out)
__global__ __launch_bounds__(256) void combine_kernel(
    const float* __restrict__ meanY,
    const u16* __restrict__ xb, const u16* __restrict__ rh,
    const float* __restrict__ h, const u16* __restrict__ z,
    const u16* __restrict__ WrT, const float* __restrict__ bl,
    float* __restrict__ out, int N)
{
    const int wave = threadIdx.x >> 6;
    const int lane = threadIdx.x & 63;
    const int quad = lane >> 4;
    const int l15  = lane & 15;
    const int node0 = blockIdx.x * 64 + wave * 16;
    if (node0 >= N) return;

    int arow = node0 + l15; if (arow >= N) arow = N - 1;
    const u16* xp  = xb + (size_t)arow * D + quad * 8;
    const u16* rhp = rh + (size_t)arow * D + quad * 8;
    bf16x8 axf[4], arh[4];
#pragma unroll
    for (int c = 0; c < 4; c++) {
        axf[c] = *(const bf16x8*)(xp + c * 32);
        arh[c] = *(const bf16x8*)(rhp + c * 32);
    }

#pragma unroll
    for (int nt = 0; nt < 8; nt++) {
        f32x4 acc = {0.f, 0.f, 0.f, 0.f};
        const u16* wr = WrT + (size_t)(nt * 16 + l15) * DC + quad * 8;
#pragma unroll
        for (int c = 0; c < 4; c++)
            acc = __builtin_amdgcn_mfma_f32_16x16x32_bf16(axf[c], *(const bf16x8*)(wr + c * 32), acc, 0, 0, 0);
#pragma unroll
        for (int c = 0; c < 4; c++)
            acc = __builtin_amdgcn_mfma_f32_16x16x32_bf16(arh[c], *(const bf16x8*)(wr + 128 + c * 32), acc, 0, 0, 0);

        int dim = nt * 16 + l15;
        float blv = bl[dim];
#pragma unroll
        for (int reg = 0; reg < 4; reg++) {
            int node = node0 + quad * 4 + reg;
            if (node < N) {
                float nv = acc[reg] + meanY[(size_t)node * D + dim] + blv;
                float zz = bf2f(z[(size_t)node * D + dim]);
                float hv = h[(size_t)node * D + dim];
                out[(size_t)node * D + dim] = (1.0f - zz) * nv + zz * hv;
            }
        }
    }
}

extern "C" void kernel_launch(void* const* d_in, const int* in_sizes, int n_in,
                              void* d_out, int out_size, void* d_ws, size_t ws_size,
                              hipStream_t stream)
{
    const float* x   = (const float*)d_in[0];
    const int*   ei  = (const int*)d_in[1];
    const float* h   = (const float*)d_in[2];
    const float* Wxr = (const float*)d_in[3];
    const float* bxr = (const float*)d_in[4];
    const float* Whr = (const float*)d_in[5];
    const float* Wxz = (const float*)d_in[6];
    const float* bxz = (const float*)d_in[7];
    const float* Whz = (const float*)d_in[8];
    const float* Wl  = (const float*)d_in[9];
    const float* bl  = (const float*)d_in[10];
    const float* Wr  = (const float*)d_in[11];
    float* out = (float*)d_out;

    const int N = in_sizes[0] / D;
    const int E = in_sizes[1] / 2;
    if (N <= 0 || E <= 0) return;

    char* ws = (char*)d_ws;
    size_t off = 0;
    auto alloc = [&](size_t bytes) -> void* {
        void* p = ws + off;
        off += (bytes + 255) & ~(size_t)255;
        return p;
    };
    u16*   rh    = (u16*)  alloc((size_t)N * D * 2);
    u16*   z     = (u16*)  alloc((size_t)N * D * 2);
    u16*   xb    = (u16*)  alloc((size_t)N * D * 2);
    u16*   y     = (u16*)  alloc((size_t)N * D * 2);
    float* meanY = (float*)alloc((size_t)N * D * 4);
    int*   deg   = (int*)  alloc((size_t)N * 4);
    int*   rstart= (int*)  alloc((size_t)N * 4);
    int*   fillc = (int*)  alloc((size_t)N * 4);
    int*   col   = (int*)  alloc((size_t)E * 4);
    u16*   WxrT  = (u16*)  alloc((size_t)D * D * 2);
    u16*   WhrT  = (u16*)  alloc((size_t)D * D * 2);
    u16*   WxzT  = (u16*)  alloc((size_t)D * D * 2);
    u16*   WhzT  = (u16*)  alloc((size_t)D * D * 2);
    u16*   WlT   = (u16*)  alloc((size_t)DC * D * 2);
    u16*   WrT   = (u16*)  alloc((size_t)DC * D * 2);
    (void)n_in; (void)out_size;
    if (off > ws_size) return;   // clean failure instead of OOB fault

    hipMemsetAsync(deg, 0, (size_t)N * 4, stream);

    const int nbx = (N * D + 255) / 256;
    const int nbh = (E + 255) / 256;
    prep_kernel<<<512 + nbx + nbh, 256, 0, stream>>>(
        Wxr, Whr, Wxz, Whz, Wl, Wr,
        WxrT, WhrT, WxzT, WhzT, WlT, WrT,
        x, xb, ei, deg, N, E, nbx);

    scan_kernel<<<1, 256, 0, stream>>>(deg, rstart, fillc, N);
    fill_kernel<<<nbh, 256, 0, stream>>>(ei, rstart, fillc, col, E);

    gates_kernel<<<(N + 63) / 64, 256, 0, stream>>>(
        xb, h, WxrT, WhrT, WxzT, WhzT, bxr, bxz, rh, z, N);

    proj_kernel<<<(N + 63) / 64, 256, 0, stream>>>(xb, rh, WlT, y, N);

    pull_kernel<<<(N + 3) / 4, 256, 0, stream>>>(rstart, deg, col, y, meanY, N);

    combine_kernel<<<(N + 63) / 64, 256, 0, stream>>>(
        meanY, xb, rh, h, z, WrT, bl, out, N);
}

// Round 9
// 382.567 us; speedup vs baseline: 15.3027x; 1.2918x over previous
//
// Inputs f32 (+ int32 edge_index), output f32, bf16 MFMA internally.
// R9: replace 122µs single-block serial prefix sum with 3-kernel parallel scan.
#include <hip/hip_runtime.h>
#include <hip/hip_bf16.h>

typedef __attribute__((ext_vector_type(8))) short bf16x8;
typedef __attribute__((ext_vector_type(4))) float f32x4;
typedef unsigned short u16;
typedef unsigned int u32;

#define D 128      // D_IN == D_H
#define DC 256     // concat dim

__device__ __forceinline__ float bf2f(u16 b) {
    u32 u = ((u32)b) << 16;
    return __uint_as_float(u);
}
__device__ __forceinline__ u16 f2bf(float f) {
    u32 u = __float_as_uint(f);
    u32 r = (u + 0x7fffu + ((u >> 16) & 1u)) >> 16;   // RNE
    return (u16)r;
}
__device__ __forceinline__ float sigmoidf_(float x) {
    float e = __builtin_amdgcn_exp2f(-1.4426950408889634f * x);
    return __builtin_amdgcn_rcpf(1.0f + e);
}
__device__ __forceinline__ bf16x8 cvt8(const float* __restrict__ p) {
    f32x4 lo = *(const f32x4*)p;
    f32x4 hi = *(const f32x4*)(p + 4);
    union { bf16x8 v; u16 s[8]; } u;
#pragma unroll
    for (int i = 0; i < 4; i++) {
        u.s[i]     = f2bf(lo[i]);
        u.s[i + 4] = f2bf(hi[i]);
    }
    return u.v;
}

// Fused prep: 6 weight transposes (f32->bf16) + xb=bf16(x) + degree histogram.
__global__ __launch_bounds__(256) void prep_kernel(
    const float* __restrict__ Wxr, const float* __restrict__ Whr,
    const float* __restrict__ Wxz, const float* __restrict__ Whz,
    const float* __restrict__ Wl,  const float* __restrict__ Wr,
    u16* __restrict__ WxrT, u16* __restrict__ WhrT,
    u16* __restrict__ WxzT, u16* __restrict__ WhzT,
    u16* __restrict__ WlT,  u16* __restrict__ WrT,
    const float* __restrict__ x, u16* __restrict__ xb,
    const int* __restrict__ ei, int* __restrict__ deg,
    int N, int E, int nbx)
{
    int bid = blockIdx.x;
    int tid = threadIdx.x;
    if (bid < 256) {                       // 4 gate weights, 128x128 each
        int m = bid >> 6;
        int g = (bid & 63) * 256 + tid;
        const float* W = (m == 0) ? Wxr : (m == 1) ? Whr : (m == 2) ? Wxz : Whz;
        u16* Wt        = (m == 0) ? WxrT : (m == 1) ? WhrT : (m == 2) ? WxzT : WhzT;
        int k = g >> 7, n = g & 127;
        Wt[n * D + k] = f2bf(W[g]);
    } else if (bid < 512) {                // Wl / Wr, 256x128 each
        int m = (bid - 256) >> 7;
        int g = ((bid - 256) & 127) * 256 + tid;
        const float* W = (m == 0) ? Wl : Wr;
        u16* Wt        = (m == 0) ? WlT : WrT;
        int k = g >> 7, n = g & 127;
        Wt[n * DC + k] = f2bf(W[g]);
    } else if (bid < 512 + nbx) {          // xb = bf16(x)
        long long g = (long long)(bid - 512) * 256 + tid;
        if (g < (long long)N * D) xb[g] = f2bf(x[g]);
    } else {                               // histogram of dst
        long long e = (long long)(bid - 512 - nbx) * 256 + tid;
        if (e < E) atomicAdd(&deg[ei[(size_t)E + e]], 1);
    }
}

// ---- parallel exclusive scan of deg -> rstart (3 small kernels) ----
__global__ __launch_bounds__(256) void scan1_kernel(
    const int* __restrict__ deg, int* __restrict__ rstart,
    int* __restrict__ bsum, int N)
{
    __shared__ int tmp[256];
    int t = threadIdx.x;
    int g = blockIdx.x * 256 + t;
    int v = (g < N) ? deg[g] : 0;
    tmp[t] = v;
    __syncthreads();
#pragma unroll
    for (int s = 1; s < 256; s <<= 1) {
        int add = (t >= s) ? tmp[t - s] : 0;
        __syncthreads();
        tmp[t] += add;
        __syncthreads();
    }
    if (g < N) rstart[g] = tmp[t] - v;          // exclusive
    if (t == 255) bsum[blockIdx.x] = tmp[255];  // block total
}

// single block: exclusive scan of nb (<=256) block sums, in place
__global__ __launch_bounds__(256) void scan2_kernel(int* __restrict__ bsum, int nb)
{
    __shared__ int tmp[256];
    int t = threadIdx.x;
    int v = (t < nb) ? bsum[t] : 0;
    tmp[t] = v;
    __syncthreads();
#pragma unroll
    for (int s = 1; s < 256; s <<= 1) {
        int add = (t >= s) ? tmp[t - s] : 0;
        __syncthreads();
        tmp[t] += add;
        __syncthreads();
    }
    if (t < nb) bsum[t] = tmp[t] - v;           // exclusive
}

__global__ __launch_bounds__(256) void scan3_kernel(
    int* __restrict__ rstart, const int* __restrict__ bsum,
    int* __restrict__ fillc, int N)
{
    int g = blockIdx.x * 256 + threadIdx.x;
    if (g < N) {
        rstart[g] += bsum[blockIdx.x];
        fillc[g] = 0;
    }
}

__global__ void fill_kernel(const int* __restrict__ ei, const int* __restrict__ row_start,
                            int* __restrict__ fillc, int* __restrict__ col, int E) {
    int e = blockIdx.x * 256 + threadIdx.x;
    if (e >= E) return;
    int src = ei[e], dst = ei[(size_t)E + e];
    int pos = atomicAdd(&fillc[dst], 1);
    col[row_start[dst] + pos] = src;
}

// ---- gates: r,z ; rh = r*h ----
__global__ __launch_bounds__(256) void gates_kernel(
    const u16* __restrict__ xb, const float* __restrict__ h,
    const u16* __restrict__ WxrT, const u16* __restrict__ WhrT,
    const u16* __restrict__ WxzT, const u16* __restrict__ WhzT,
    const float* __restrict__ bxr, const float* __restrict__ bxz,
    u16* __restrict__ rh, u16* __restrict__ zo, int N)
{
    const int wave = threadIdx.x >> 6;
    const int lane = threadIdx.x & 63;
    const int quad = lane >> 4;
    const int l15  = lane & 15;
    const int node0 = blockIdx.x * 64 + wave * 16;
    if (node0 >= N) return;

    int arow = node0 + l15; if (arow >= N) arow = N - 1;
    const u16*   xp = xb + (size_t)arow * D + quad * 8;
    const float* hp = h  + (size_t)arow * D + quad * 8;
    bf16x8 ax[4], ah[4];
#pragma unroll
    for (int c = 0; c < 4; c++) {
        ax[c] = *(const bf16x8*)(xp + c * 32);
        ah[c] = cvt8(hp + c * 32);
    }

#pragma unroll
    for (int nt = 0; nt < 8; nt++) {
        f32x4 accr = {0.f, 0.f, 0.f, 0.f}, accz = {0.f, 0.f, 0.f, 0.f};
        const u16* wrx = WxrT + (size_t)(nt * 16 + l15) * D + quad * 8;
        const u16* wrh = WhrT + (size_t)(nt * 16 + l15) * D + quad * 8;
        const u16* wzx = WxzT + (size_t)(nt * 16 + l15) * D + quad * 8;
        const u16* wzh = WhzT + (size_t)(nt * 16 + l15) * D + quad * 8;
#pragma unroll
        for (int c = 0; c < 4; c++) {
            bf16x8 b0 = *(const bf16x8*)(wrx + c * 32);
            bf16x8 b1 = *(const bf16x8*)(wrh + c * 32);
            bf16x8 b2 = *(const bf16x8*)(wzx + c * 32);
            bf16x8 b3 = *(const bf16x8*)(wzh + c * 32);
            accr = __builtin_amdgcn_mfma_f32_16x16x32_bf16(ax[c], b0, accr, 0, 0, 0);
            accr = __builtin_amdgcn_mfma_f32_16x16x32_bf16(ah[c], b1, accr, 0, 0, 0);
            accz = __builtin_amdgcn_mfma_f32_16x16x32_bf16(ax[c], b2, accz, 0, 0, 0);
            accz = __builtin_amdgcn_mfma_f32_16x16x32_bf16(ah[c], b3, accz, 0, 0, 0);
        }
        int dim = nt * 16 + l15;
        float br = bxr[dim];
        float bz = bxz[dim];
#pragma unroll
        for (int reg = 0; reg < 4; reg++) {
            int node = node0 + quad * 4 + reg;
            if (node < N) {
                float r  = sigmoidf_(accr[reg] + br);
                float zz = sigmoidf_(accz[reg] + bz);
                float hv = h[(size_t)node * D + dim];
                rh[(size_t)node * D + dim] = f2bf(r * hv);
                zo[(size_t)node * D + dim] = f2bf(zz);
            }
        }
    }
}

// ---- proj: y = [xb | rh] @ Wl   (per node, K=256, bf16 out) ----
__global__ __launch_bounds__(256) void proj_kernel(
    const u16* __restrict__ xb, const u16* __restrict__ rh,
    const u16* __restrict__ WlT, u16* __restrict__ y, int N)
{
    const int wave = threadIdx.x >> 6;
    const int lane = threadIdx.x & 63;
    const int quad = lane >> 4;
    const int l15  = lane & 15;
    const int node0 = blockIdx.x * 64 + wave * 16;
    if (node0 >= N) return;

    int arow = node0 + l15; if (arow >= N) arow = N - 1;
    const u16* xp  = xb + (size_t)arow * D + quad * 8;
    const u16* rhp = rh + (size_t)arow * D + quad * 8;
    bf16x8 axf[4], arh[4];
#pragma unroll
    for (int c = 0; c < 4; c++) {
        axf[c] = *(const bf16x8*)(xp + c * 32);
        arh[c] = *(const bf16x8*)(rhp + c * 32);
    }

#pragma unroll
    for (int nt = 0; nt < 8; nt++) {
        f32x4 acc = {0.f, 0.f, 0.f, 0.f};
        const u16* wl = WlT + (size_t)(nt * 16 + l15) * DC + quad * 8;
#pragma unroll
        for (int c = 0; c < 4; c++)
            acc = __builtin_amdgcn_mfma_f32_16x16x32_bf16(axf[c], *(const bf16x8*)(wl + c * 32), acc, 0, 0, 0);
#pragma unroll
        for (int c = 0; c < 4; c++)
            acc = __builtin_amdgcn_mfma_f32_16x16x32_bf16(arh[c], *(const bf16x8*)(wl + 128 + c * 32), acc, 0, 0, 0);

        int dim = nt * 16 + l15;
#pragma unroll
        for (int reg = 0; reg < 4; reg++) {
            int node = node0 + quad * 4 + reg;
            if (node < N)
                y[(size_t)node * D + dim] = f2bf(acc[reg]);
        }
    }
}

// ---- pull: meanY[n] = mean over edges of y[src]  (1 wave/node, 4 edges/iter) ----
__global__ __launch_bounds__(256) void pull_kernel(
    const int* __restrict__ row_start, const int* __restrict__ deg,
    const int* __restrict__ col, const u16* __restrict__ y,
    float* __restrict__ meanY, int N)
{
    const int wave = threadIdx.x >> 6;
    const int lane = threadIdx.x & 63;
    const int node = blockIdx.x * 4 + wave;
    if (node >= N) return;

    const int base = row_start[node];
    const int d    = deg[node];
    const int g    = lane >> 4;       // edge sub-group 0..3
    const int l15  = lane & 15;       // 16B segment of the y row

    float a[8] = {0.f,0.f,0.f,0.f,0.f,0.f,0.f,0.f};
    for (int i = 0; i < d; i += 4) {
        int e = i + g;
        if (e < d) {
            int s = col[base + e];
            bf16x8 v = *(const bf16x8*)(y + (size_t)s * D + l15 * 8);
#pragma unroll
            for (int j = 0; j < 8; j++) a[j] += bf2f((u16)v[j]);
        }
    }
#pragma unroll
    for (int j = 0; j < 8; j++) {
        a[j] += __shfl_xor(a[j], 16, 64);
        a[j] += __shfl_xor(a[j], 32, 64);
    }
    if (lane < 16) {
        float inv = 1.0f / (float)(d > 0 ? d : 1);
        f32x4 o0 = {a[0]*inv, a[1]*inv, a[2]*inv, a[3]*inv};
        f32x4 o1 = {a[4]*inv, a[5]*inv, a[6]*inv, a[7]*inv};
        float* mp = meanY + (size_t)node * D + l15 * 8;
        *(f32x4*)mp       = o0;
        *(f32x4*)(mp + 4) = o1;
    }
}

// n = meanY + bl + [xb|rh]@Wr;  out = (1-z)*n + z*h  (f32 out)
__global__ __launch_bounds__(256) void combine_kernel(
    const float* __restrict__ meanY,
    const u16* __restrict__ xb, const u16* __restrict__ rh,
    const float* __restrict__ h, const u16* __restrict__ z,
    const u16* __restrict__ WrT, const float* __restrict__ bl,
    float* __restrict__ out, int N)
{
    const int wave = threadIdx.x >> 6;
    const int lane = threadIdx.x & 63;
    const int quad = lane >> 4;
    const int l15  = lane & 15;
    const int node0 = blockIdx.x * 64 + wave * 16;
    if (node0 >= N) return;

    int arow = node0 + l15; if (arow >= N) arow = N - 1;
    const u16* xp  = xb + (size_t)arow * D + quad * 8;
    const u16* rhp = rh + (size_t)arow * D + quad * 8;
    bf16x8 axf[4], arh[4];
#pragma unroll
    for (int c = 0; c < 4; c++) {
        axf[c] = *(const bf16x8*)(xp + c * 32);
        arh[c] = *(const bf16x8*)(rhp + c * 32);
    }

#pragma unroll
    for (int nt = 0; nt < 8; nt++) {
        f32x4 acc = {0.f, 0.f, 0.f, 0.f};
        const u16* wr = WrT + (size_t)(nt * 16 + l15) * DC + quad * 8;
#pragma unroll
        for (int c = 0; c < 4; c++)
            acc = __builtin_amdgcn_mfma_f32_16x16x32_bf16(axf[c], *(const bf16x8*)(wr + c * 32), acc, 0, 0, 0);
#pragma unroll
        for (int c = 0; c < 4; c++)
            acc = __builtin_amdgcn_mfma_f32_16x16x32_bf16(arh[c], *(const bf16x8*)(wr + 128 + c * 32), acc, 0, 0, 0);

        int dim = nt * 16 + l15;
        float blv = bl[dim];
#pragma unroll
        for (int reg = 0; reg < 4; reg++) {
            int node = node0 + quad * 4 + reg;
            if (node < N) {
                float nv = acc[reg] + meanY[(size_t)node * D + dim] + blv;
                float zz = bf2f(z[(size_t)node * D + dim]);
                float hv = h[(size_t)node * D + dim];
                out[(size_t)node * D + dim] = (1.0f - zz) * nv + zz * hv;
            }
        }
    }
}

extern "C" void kernel_launch(void* const* d_in, const int* in_sizes, int n_in,
                              void* d_out, int out_size, void* d_ws, size_t ws_size,
                              hipStream_t stream)
{
    const float* x   = (const float*)d_in[0];
    const int*   ei  = (const int*)d_in[1];
    const float* h   = (const float*)d_in[2];
    const float* Wxr = (const float*)d_in[3];
    const float* bxr = (const float*)d_in[4];
    const float* Whr = (const float*)d_in[5];
    const float* Wxz = (const float*)d_in[6];
    const float* bxz = (const float*)d_in[7];
    const float* Whz = (const float*)d_in[8];
    const float* Wl  = (const float*)d_in[9];
    const float* bl  = (const float*)d_in[10];
    const float* Wr  = (const float*)d_in[11];
    float* out = (float*)d_out;

    const int N = in_sizes[0] / D;
    const int E = in_sizes[1] / 2;
    if (N <= 0 || E <= 0) return;

    const int nbn = (N + 255) / 256;        // blocks over nodes
    if (nbn > 256) return;                  // scan2 capacity (N<=65536); N=50000 ok

    char* ws = (char*)d_ws;
    size_t off = 0;
    auto alloc = [&](size_t bytes) -> void* {
        void* p = ws + off;
        off += (bytes + 255) & ~(size_t)255;
        return p;
    };
    u16*   rh    = (u16*)  alloc((size_t)N * D * 2);
    u16*   z     = (u16*)  alloc((size_t)N * D * 2);
    u16*   xb    = (u16*)  alloc((size_t)N * D * 2);
    u16*   y     = (u16*)  alloc((size_t)N * D * 2);
    float* meanY = (float*)alloc((size_t)N * D * 4);
    int*   deg   = (int*)  alloc((size_t)N * 4);
    int*   rstart= (int*)  alloc((size_t)N * 4);
    int*   fillc = (int*)  alloc((size_t)N * 4);
    int*   bsum  = (int*)  alloc((size_t)256 * 4);
    int*   col   = (int*)  alloc((size_t)E * 4);
    u16*   WxrT  = (u16*)  alloc((size_t)D * D * 2);
    u16*   WhrT  = (u16*)  alloc((size_t)D * D * 2);
    u16*   WxzT  = (u16*)  alloc((size_t)D * D * 2);
    u16*   WhzT  = (u16*)  alloc((size_t)D * D * 2);
    u16*   WlT   = (u16*)  alloc((size_t)DC * D * 2);
    u16*   WrT   = (u16*)  alloc((size_t)DC * D * 2);
    (void)n_in; (void)out_size;
    if (off > ws_size) return;   // clean failure instead of OOB fault

    hipMemsetAsync(deg, 0, (size_t)N * 4, stream);

    const int nbx = (N * D + 255) / 256;
    const int nbh = (E + 255) / 256;
    prep_kernel<<<512 + nbx + nbh, 256, 0, stream>>>(
        Wxr, Whr, Wxz, Whz, Wl, Wr,
        WxrT, WhrT, WxzT, WhzT, WlT, WrT,
        x, xb, ei, deg, N, E, nbx);

    scan1_kernel<<<nbn, 256, 0, stream>>>(deg, rstart, bsum, N);
    scan2_kernel<<<1, 256, 0, stream>>>(bsum, nbn);
    scan3_kernel<<<nbn, 256, 0, stream>>>(rstart, bsum, fillc, N);
    fill_kernel<<<nbh, 256, 0, stream>>>(ei, rstart, fillc, col, E);

    gates_kernel<<<(N + 63) / 64, 256, 0, stream>>>(
        xb, h, WxrT, WhrT, WxzT, WhzT, bxr, bxz, rh, z, N);

    proj_kernel<<<(N + 63) / 64, 256, 0, stream>>>(xb, rh, WlT, y, N);

    pull_kernel<<<(N + 3) / 4, 256, 0, stream>>>(rstart, deg, col, y, meanY, N);

    combine_kernel<<<(N + 63) / 64, 256, 0, stream>>>(
        meanY, xb, rh, h, z, WrT, bl, out, N);
}

// Round 11
// 376.872 us; speedup vs baseline: 15.5340x; 1.0151x over previous
//
// Inputs f32 (+ int32 edge_index), output f32, bf16 MFMA internally.
// R11 = R10 with the LDS->global store loops fixed (they covered only half
// the 16x128 tile: 2 iters/seg&7 -> 4 iters/seg&15).
#include <hip/hip_runtime.h>
#include <hip/hip_bf16.h>

typedef __attribute__((ext_vector_type(8))) short bf16x8;
typedef __attribute__((ext_vector_type(4))) short s16x4;
typedef __attribute__((ext_vector_type(4))) float f32x4;
typedef unsigned short u16;
typedef unsigned int u32;

#define D 128      // D_IN == D_H
#define DC 256     // concat dim
// LDS tile: 16 rows x 128 u16, XOR-swizzled (16B-aligned, low bank conflict)
#define SWZ(row, dim) (((row) << 7) + ((dim) ^ (((row) & 15) << 3)))

__device__ __forceinline__ float bf2f(u16 b) {
    u32 u = ((u32)b) << 16;
    return __uint_as_float(u);
}
__device__ __forceinline__ u16 f2bf(float f) {
    u32 u = __float_as_uint(f);
    u32 r = (u + 0x7fffu + ((u >> 16) & 1u)) >> 16;   // RNE
    return (u16)r;
}
__device__ __forceinline__ float sigmoidf_(float x) {
    float e = __builtin_amdgcn_exp2f(-1.4426950408889634f * x);
    return __builtin_amdgcn_rcpf(1.0f + e);
}
__device__ __forceinline__ bf16x8 cvt8(const float* __restrict__ p) {
    f32x4 lo = *(const f32x4*)p;
    f32x4 hi = *(const f32x4*)(p + 4);
    union { bf16x8 v; u16 s[8]; } u;
#pragma unroll
    for (int i = 0; i < 4; i++) {
        u.s[i]     = f2bf(lo[i]);
        u.s[i + 4] = f2bf(hi[i]);
    }
    return u.v;
}

// Fused prep: 6 weight transposes (f32->bf16) + xb=bf16(x) + degree histogram.
__global__ __launch_bounds__(256) void prep_kernel(
    const float* __restrict__ Wxr, const float* __restrict__ Whr,
    const float* __restrict__ Wxz, const float* __restrict__ Whz,
    const float* __restrict__ Wl,  const float* __restrict__ Wr,
    u16* __restrict__ WxrT, u16* __restrict__ WhrT,
    u16* __restrict__ WxzT, u16* __restrict__ WhzT,
    u16* __restrict__ WlT,  u16* __restrict__ WrT,
    const float* __restrict__ x, u16* __restrict__ xb,
    const int* __restrict__ ei, int* __restrict__ deg,
    int N, int E, int nbx)
{
    int bid = blockIdx.x;
    int tid = threadIdx.x;
    if (bid < 256) {                       // 4 gate weights, 128x128 each
        int m = bid >> 6;
        int g = (bid & 63) * 256 + tid;
        const float* W = (m == 0) ? Wxr : (m == 1) ? Whr : (m == 2) ? Wxz : Whz;
        u16* Wt        = (m == 0) ? WxrT : (m == 1) ? WhrT : (m == 2) ? WxzT : WhzT;
        int k = g >> 7, n = g & 127;
        Wt[n * D + k] = f2bf(W[g]);
    } else if (bid < 512) {                // Wl / Wr, 256x128 each
        int m = (bid - 256) >> 7;
        int g = ((bid - 256) & 127) * 256 + tid;
        const float* W = (m == 0) ? Wl : Wr;
        u16* Wt        = (m == 0) ? WlT : WrT;
        int k = g >> 7, n = g & 127;
        Wt[n * DC + k] = f2bf(W[g]);
    } else if (bid < 512 + nbx) {          // xb = bf16(x)
        long long g = (long long)(bid - 512) * 256 + tid;
        if (g < (long long)N * D) xb[g] = f2bf(x[g]);
    } else {                               // histogram of dst
        long long e = (long long)(bid - 512 - nbx) * 256 + tid;
        if (e < E) atomicAdd(&deg[ei[(size_t)E + e]], 1);
    }
}

// ---- parallel exclusive scan of deg -> rstart ----
__global__ __launch_bounds__(256) void scan1_kernel(
    const int* __restrict__ deg, int* __restrict__ rstart,
    int* __restrict__ bsum, int N)
{
    __shared__ int tmp[256];
    int t = threadIdx.x;
    int g = blockIdx.x * 256 + t;
    int v = (g < N) ? deg[g] : 0;
    tmp[t] = v;
    __syncthreads();
#pragma unroll
    for (int s = 1; s < 256; s <<= 1) {
        int add = (t >= s) ? tmp[t - s] : 0;
        __syncthreads();
        tmp[t] += add;
        __syncthreads();
    }
    if (g < N) rstart[g] = tmp[t] - v;
    if (t == 255) bsum[blockIdx.x] = tmp[255];
}

__global__ __launch_bounds__(256) void scan2_kernel(int* __restrict__ bsum, int nb)
{
    __shared__ int tmp[256];
    int t = threadIdx.x;
    int v = (t < nb) ? bsum[t] : 0;
    tmp[t] = v;
    __syncthreads();
#pragma unroll
    for (int s = 1; s < 256; s <<= 1) {
        int add = (t >= s) ? tmp[t - s] : 0;
        __syncthreads();
        tmp[t] += add;
        __syncthreads();
    }
    if (t < nb) bsum[t] = tmp[t] - v;
}

__global__ __launch_bounds__(256) void scan3_kernel(
    int* __restrict__ rstart, const int* __restrict__ bsum,
    int* __restrict__ fillc, int N)
{
    int g = blockIdx.x * 256 + threadIdx.x;
    if (g < N) {
        rstart[g] += bsum[blockIdx.x];
        fillc[g] = 0;
    }
}

__global__ void fill_kernel(const int* __restrict__ ei, const int* __restrict__ row_start,
                            int* __restrict__ fillc, int* __restrict__ col, int E) {
    int e = blockIdx.x * 256 + threadIdx.x;
    if (e >= E) return;
    int src = ei[e], dst = ei[(size_t)E + e];
    int pos = atomicAdd(&fillc[dst], 1);
    col[row_start[dst] + pos] = src;
}

// ---- fused: gates (r,z) -> rh in LDS -> y=[xb|rh]@Wl, w=[xb|rh]@Wr ----
__global__ __launch_bounds__(256) void fused_kernel(
    const u16* __restrict__ xb, const float* __restrict__ h,
    const u16* __restrict__ WxrT, const u16* __restrict__ WhrT,
    const u16* __restrict__ WxzT, const u16* __restrict__ WhzT,
    const u16* __restrict__ WlT,  const u16* __restrict__ WrT,
    const float* __restrict__ bxr, const float* __restrict__ bxz,
    u16* __restrict__ zo, u16* __restrict__ yo, u16* __restrict__ wo, int N)
{
    __shared__ u16 lds[4][2][16 * 128];
    const int wave = threadIdx.x >> 6;
    const int lane = threadIdx.x & 63;
    const int quad = lane >> 4;
    const int l15  = lane & 15;
    const int node0 = blockIdx.x * 64 + wave * 16;
    if (node0 >= N) return;
    u16* L0 = lds[wave][0];   // rh tile, later w-stage
    u16* L1 = lds[wave][1];   // z-stage, later y-stage

    int arow = node0 + l15; if (arow >= N) arow = N - 1;
    const u16*   xp = xb + (size_t)arow * D + quad * 8;
    const float* hp = h  + (size_t)arow * D + quad * 8;
    bf16x8 ax[4], ah[4];
#pragma unroll
    for (int c = 0; c < 4; c++) {
        ax[c] = *(const bf16x8*)(xp + c * 32);
        ah[c] = cvt8(hp + c * 32);
    }

    // ---- gates phase ----
#pragma unroll
    for (int nt = 0; nt < 8; nt++) {
        f32x4 accr = {0.f, 0.f, 0.f, 0.f}, accz = {0.f, 0.f, 0.f, 0.f};
        const u16* wrx = WxrT + (size_t)(nt * 16 + l15) * D + quad * 8;
        const u16* wrh = WhrT + (size_t)(nt * 16 + l15) * D + quad * 8;
        const u16* wzx = WxzT + (size_t)(nt * 16 + l15) * D + quad * 8;
        const u16* wzh = WhzT + (size_t)(nt * 16 + l15) * D + quad * 8;
#pragma unroll
        for (int c = 0; c < 4; c++) {
            accr = __builtin_amdgcn_mfma_f32_16x16x32_bf16(ax[c], *(const bf16x8*)(wrx + c * 32), accr, 0, 0, 0);
            accr = __builtin_amdgcn_mfma_f32_16x16x32_bf16(ah[c], *(const bf16x8*)(wrh + c * 32), accr, 0, 0, 0);
            accz = __builtin_amdgcn_mfma_f32_16x16x32_bf16(ax[c], *(const bf16x8*)(wzx + c * 32), accz, 0, 0, 0);
            accz = __builtin_amdgcn_mfma_f32_16x16x32_bf16(ah[c], *(const bf16x8*)(wzh + c * 32), accz, 0, 0, 0);
        }
        int dim = nt * 16 + l15;
        float br = bxr[dim];
        float bz = bxz[dim];
#pragma unroll
        for (int reg = 0; reg < 4; reg++) {
            int row = quad * 4 + reg;
            int hn = node0 + row; if (hn >= N) hn = N - 1;
            float hv = h[(size_t)hn * D + dim];
            float r  = sigmoidf_(accr[reg] + br);
            float zz = sigmoidf_(accz[reg] + bz);
            L0[SWZ(row, dim)] = f2bf(r * hv);
            L1[SWZ(row, dim)] = f2bf(zz);
        }
    }

    // rh A-fragments from LDS (C-layout -> A-layout transform)
    bf16x8 arh[4];
#pragma unroll
    for (int c = 0; c < 4; c++)
        arh[c] = *(const bf16x8*)&L0[SWZ(l15, c * 32 + quad * 8)];

    // store z coalesced: full 16x128 tile = 256 bf16x8 stores = 4 iters
#pragma unroll
    for (int it = 0; it < 4; it++) {
        int idx = it * 64 + lane;
        int row = idx >> 4, seg = idx & 15;
        int node = node0 + row;
        if (node < N)
            *(bf16x8*)(zo + (size_t)node * D + seg * 8) = *(const bf16x8*)&L1[SWZ(row, seg * 8)];
    }

    // ---- proj phase: y (Wl) into L1, w (Wr) into L0 ----
#pragma unroll
    for (int nt = 0; nt < 8; nt++) {
        f32x4 ay = {0.f, 0.f, 0.f, 0.f}, aw = {0.f, 0.f, 0.f, 0.f};
        const u16* pl = WlT + (size_t)(nt * 16 + l15) * DC + quad * 8;
        const u16* pr = WrT + (size_t)(nt * 16 + l15) * DC + quad * 8;
#pragma unroll
        for (int c = 0; c < 4; c++) {
            ay = __builtin_amdgcn_mfma_f32_16x16x32_bf16(ax[c],  *(const bf16x8*)(pl + c * 32),       ay, 0, 0, 0);
            ay = __builtin_amdgcn_mfma_f32_16x16x32_bf16(arh[c], *(const bf16x8*)(pl + 128 + c * 32), ay, 0, 0, 0);
            aw = __builtin_amdgcn_mfma_f32_16x16x32_bf16(ax[c],  *(const bf16x8*)(pr + c * 32),       aw, 0, 0, 0);
            aw = __builtin_amdgcn_mfma_f32_16x16x32_bf16(arh[c], *(const bf16x8*)(pr + 128 + c * 32), aw, 0, 0, 0);
        }
        int dim = nt * 16 + l15;
#pragma unroll
        for (int reg = 0; reg < 4; reg++) {
            int row = quad * 4 + reg;
            L1[SWZ(row, dim)] = f2bf(ay[reg]);
            L0[SWZ(row, dim)] = f2bf(aw[reg]);
        }
    }

    // store y (L1) and w (L0) coalesced — full tile, 4 iters
#pragma unroll
    for (int it = 0; it < 4; it++) {
        int idx = it * 64 + lane;
        int row = idx >> 4, seg = idx & 15;
        int node = node0 + row;
        if (node < N) {
            *(bf16x8*)(yo + (size_t)node * D + seg * 8) = *(const bf16x8*)&L1[SWZ(row, seg * 8)];
            *(bf16x8*)(wo + (size_t)node * D + seg * 8) = *(const bf16x8*)&L0[SWZ(row, seg * 8)];
        }
    }
}

// ---- pull: meanY[n] = mean over edges of y[src]  (1 wave/node, 4 edges/iter) ----
__global__ __launch_bounds__(256) void pull_kernel(
    const int* __restrict__ row_start, const int* __restrict__ deg,
    const int* __restrict__ col, const u16* __restrict__ y,
    u16* __restrict__ meanY, int N)
{
    const int wave = threadIdx.x >> 6;
    const int lane = threadIdx.x & 63;
    const int node = blockIdx.x * 4 + wave;
    if (node >= N) return;

    const int base = row_start[node];
    const int d    = deg[node];
    const int g    = lane >> 4;
    const int l15  = lane & 15;

    float a[8] = {0.f,0.f,0.f,0.f,0.f,0.f,0.f,0.f};
    for (int i = 0; i < d; i += 4) {
        int e = i + g;
        if (e < d) {
            int s = col[base + e];
            bf16x8 v = *(const bf16x8*)(y + (size_t)s * D + l15 * 8);
#pragma unroll
            for (int j = 0; j < 8; j++) a[j] += bf2f((u16)v[j]);
        }
    }
#pragma unroll
    for (int j = 0; j < 8; j++) {
        a[j] += __shfl_xor(a[j], 16, 64);
        a[j] += __shfl_xor(a[j], 32, 64);
    }
    if (lane < 16) {
        float inv = 1.0f / (float)(d > 0 ? d : 1);
        union { bf16x8 v; u16 s[8]; } o;
#pragma unroll
        for (int j = 0; j < 8; j++) o.s[j] = f2bf(a[j] * inv);
        *(bf16x8*)(meanY + (size_t)node * D + l15 * 8) = o.v;
    }
}

// out = (1-z)*(meanY + bl + w) + z*h   (pure elementwise, f32 out)
__global__ __launch_bounds__(256) void combine_kernel(
    const u16* __restrict__ z, const u16* __restrict__ w,
    const u16* __restrict__ meanY, const float* __restrict__ h,
    const float* __restrict__ bl, float* __restrict__ out, long long total)
{
    long long g = ((long long)blockIdx.x * 256 + threadIdx.x) * 4;
    if (g >= total) return;
    int dim = (int)(g & (D - 1));
    s16x4 zv = *(const s16x4*)(z + g);
    s16x4 wv = *(const s16x4*)(w + g);
    s16x4 mv = *(const s16x4*)(meanY + g);
    f32x4 hv = *(const f32x4*)(h + g);
    f32x4 bv = *(const f32x4*)(bl + dim);
    f32x4 o;
#pragma unroll
    for (int j = 0; j < 4; j++) {
        float zz = bf2f((u16)zv[j]);
        float nv = bf2f((u16)mv[j]) + bv[j] + bf2f((u16)wv[j]);
        o[j] = (1.0f - zz) * nv + zz * hv[j];
    }
    *(f32x4*)(out + g) = o;
}

extern "C" void kernel_launch(void* const* d_in, const int* in_sizes, int n_in,
                              void* d_out, int out_size, void* d_ws, size_t ws_size,
                              hipStream_t stream)
{
    const float* x   = (const float*)d_in[0];
    const int*   ei  = (const int*)d_in[1];
    const float* h   = (const float*)d_in[2];
    const float* Wxr = (const float*)d_in[3];
    const float* bxr = (const float*)d_in[4];
    const float* Whr = (const float*)d_in[5];
    const float* Wxz = (const float*)d_in[6];
    const float* bxz = (const float*)d_in[7];
    const float* Whz = (const float*)d_in[8];
    const float* Wl  = (const float*)d_in[9];
    const float* bl  = (const float*)d_in[10];
    const float* Wr  = (const float*)d_in[11];
    float* out = (float*)d_out;

    const int N = in_sizes[0] / D;
    const int E = in_sizes[1] / 2;
    if (N <= 0 || E <= 0) return;

    const int nbn = (N + 255) / 256;
    if (nbn > 256) return;                  // scan2 capacity; N=50000 ok

    char* ws = (char*)d_ws;
    size_t off = 0;
    auto alloc = [&](size_t bytes) -> void* {
        void* p = ws + off;
        off += (bytes + 255) & ~(size_t)255;
        return p;
    };
    u16*   z     = (u16*)  alloc((size_t)N * D * 2);
    u16*   xbuf  = (u16*)  alloc((size_t)N * D * 2);
    u16*   y     = (u16*)  alloc((size_t)N * D * 2);
    u16*   w     = (u16*)  alloc((size_t)N * D * 2);
    u16*   meanY = (u16*)  alloc((size_t)N * D * 2);
    int*   deg   = (int*)  alloc((size_t)N * 4);
    int*   rstart= (int*)  alloc((size_t)N * 4);
    int*   fillc = (int*)  alloc((size_t)N * 4);
    int*   bsum  = (int*)  alloc((size_t)256 * 4);
    int*   col   = (int*)  alloc((size_t)E * 4);
    u16*   WxrT  = (u16*)  alloc((size_t)D * D * 2);
    u16*   WhrT  = (u16*)  alloc((size_t)D * D * 2);
    u16*   WxzT  = (u16*)  alloc((size_t)D * D * 2);
    u16*   WhzT  = (u16*)  alloc((size_t)D * D * 2);
    u16*   WlT   = (u16*)  alloc((size_t)DC * D * 2);
    u16*   WrT   = (u16*)  alloc((size_t)DC * D * 2);
    (void)n_in; (void)out_size;
    if (off > ws_size) return;   // clean failure instead of OOB fault

    hipMemsetAsync(deg, 0, (size_t)N * 4, stream);

    const int nbx = (N * D + 255) / 256;
    const int nbh = (E + 255) / 256;
    prep_kernel<<<512 + nbx + nbh, 256, 0, stream>>>(
        Wxr, Whr, Wxz, Whz, Wl, Wr,
        WxrT, WhrT, WxzT, WhzT, WlT, WrT,
        x, xbuf, ei, deg, N, E, nbx);

    scan1_kernel<<<nbn, 256, 0, stream>>>(deg, rstart, bsum, N);
    scan2_kernel<<<1, 256, 0, stream>>>(bsum, nbn);
    scan3_kernel<<<nbn, 256, 0, stream>>>(rstart, bsum, fillc, N);
    fill_kernel<<<nbh, 256, 0, stream>>>(ei, rstart, fillc, col, E);

    fused_kernel<<<(N + 63) / 64, 256, 0, stream>>>(
        xbuf, h, WxrT, WhrT, WxzT, WhzT, WlT, WrT, bxr, bxz, z, y, w, N);

    pull_kernel<<<(N + 3) / 4, 256, 0, stream>>>(rstart, deg, col, y, meanY, N);

    long long total = (long long)N * D;
    combine_kernel<<<(int)((total / 4 + 255) / 256), 256, 0, stream>>>(
        z, w, meanY, h, bl, out, total);
}

// Round 12
// 328.421 us; speedup vs baseline: 17.8256x; 1.1475x over previous
//
// Inputs f32 (+ int32 edge_index), output f32, bf16 MFMA internally.
// R12: fused kernel reworked: M=32 nodes/wave (2 MFMA tile-sets per weight
// fragment -> load:MFMA 1:2), h staged bf16 in LDS (no scalar h loads),
// z/w scattered from regs (keeps LDS at 32KB/block -> 5 blocks/CU).
#include <hip/hip_runtime.h>
#include <hip/hip_bf16.h>

typedef __attribute__((ext_vector_type(8))) short bf16x8;
typedef __attribute__((ext_vector_type(4))) short s16x4;
typedef __attribute__((ext_vector_type(4))) float f32x4;
typedef unsigned short u16;
typedef unsigned int u32;

#define D 128      // D_IN == D_H
#define DC 256     // concat dim
// LDS tile: 16 rows x 128 u16, XOR-swizzled (16B-aligned, low bank conflict)
#define SWZ(row, dim) (((row) << 7) + ((dim) ^ (((row) & 15) << 3)))

__device__ __forceinline__ float bf2f(u16 b) {
    u32 u = ((u32)b) << 16;
    return __uint_as_float(u);
}
__device__ __forceinline__ u16 f2bf(float f) {
    u32 u = __float_as_uint(f);
    u32 r = (u + 0x7fffu + ((u >> 16) & 1u)) >> 16;   // RNE
    return (u16)r;
}
__device__ __forceinline__ float sigmoidf_(float x) {
    float e = __builtin_amdgcn_exp2f(-1.4426950408889634f * x);
    return __builtin_amdgcn_rcpf(1.0f + e);
}
__device__ __forceinline__ bf16x8 cvt8(const float* __restrict__ p) {
    f32x4 lo = *(const f32x4*)p;
    f32x4 hi = *(const f32x4*)(p + 4);
    union { bf16x8 v; u16 s[8]; } u;
#pragma unroll
    for (int i = 0; i < 4; i++) {
        u.s[i]     = f2bf(lo[i]);
        u.s[i + 4] = f2bf(hi[i]);
    }
    return u.v;
}

// Fused prep: 6 weight transposes (f32->bf16) + xb=bf16(x) + degree histogram.
__global__ __launch_bounds__(256) void prep_kernel(
    const float* __restrict__ Wxr, const float* __restrict__ Whr,
    const float* __restrict__ Wxz, const float* __restrict__ Whz,
    const float* __restrict__ Wl,  const float* __restrict__ Wr,
    u16* __restrict__ WxrT, u16* __restrict__ WhrT,
    u16* __restrict__ WxzT, u16* __restrict__ WhzT,
    u16* __restrict__ WlT,  u16* __restrict__ WrT,
    const float* __restrict__ x, u16* __restrict__ xb,
    const int* __restrict__ ei, int* __restrict__ deg,
    int N, int E, int nbx)
{
    int bid = blockIdx.x;
    int tid = threadIdx.x;
    if (bid < 256) {                       // 4 gate weights, 128x128 each
        int m = bid >> 6;
        int g = (bid & 63) * 256 + tid;
        const float* W = (m == 0) ? Wxr : (m == 1) ? Whr : (m == 2) ? Wxz : Whz;
        u16* Wt        = (m == 0) ? WxrT : (m == 1) ? WhrT : (m == 2) ? WxzT : WhzT;
        int k = g >> 7, n = g & 127;
        Wt[n * D + k] = f2bf(W[g]);
    } else if (bid < 512) {                // Wl / Wr, 256x128 each
        int m = (bid - 256) >> 7;
        int g = ((bid - 256) & 127) * 256 + tid;
        const float* W = (m == 0) ? Wl : Wr;
        u16* Wt        = (m == 0) ? WlT : WrT;
        int k = g >> 7, n = g & 127;
        Wt[n * DC + k] = f2bf(W[g]);
    } else if (bid < 512 + nbx) {          // xb = bf16(x)
        long long g = (long long)(bid - 512) * 256 + tid;
        if (g < (long long)N * D) xb[g] = f2bf(x[g]);
    } else {                               // histogram of dst
        long long e = (long long)(bid - 512 - nbx) * 256 + tid;
        if (e < E) atomicAdd(&deg[ei[(size_t)E + e]], 1);
    }
}

// ---- parallel exclusive scan of deg -> rstart ----
__global__ __launch_bounds__(256) void scan1_kernel(
    const int* __restrict__ deg, int* __restrict__ rstart,
    int* __restrict__ bsum, int N)
{
    __shared__ int tmp[256];
    int t = threadIdx.x;
    int g = blockIdx.x * 256 + t;
    int v = (g < N) ? deg[g] : 0;
    tmp[t] = v;
    __syncthreads();
#pragma unroll
    for (int s = 1; s < 256; s <<= 1) {
        int add = (t >= s) ? tmp[t - s] : 0;
        __syncthreads();
        tmp[t] += add;
        __syncthreads();
    }
    if (g < N) rstart[g] = tmp[t] - v;
    if (t == 255) bsum[blockIdx.x] = tmp[255];
}

__global__ __launch_bounds__(256) void scan2_kernel(int* __restrict__ bsum, int nb)
{
    __shared__ int tmp[256];
    int t = threadIdx.x;
    int v = (t < nb) ? bsum[t] : 0;
    tmp[t] = v;
    __syncthreads();
#pragma unroll
    for (int s = 1; s < 256; s <<= 1) {
        int add = (t >= s) ? tmp[t - s] : 0;
        __syncthreads();
        tmp[t] += add;
        __syncthreads();
    }
    if (t < nb) bsum[t] = tmp[t] - v;
}

__global__ __launch_bounds__(256) void scan3_kernel(
    int* __restrict__ rstart, const int* __restrict__ bsum,
    int* __restrict__ fillc, int N)
{
    int g = blockIdx.x * 256 + threadIdx.x;
    if (g < N) {
        rstart[g] += bsum[blockIdx.x];
        fillc[g] = 0;
    }
}

__global__ void fill_kernel(const int* __restrict__ ei, const int* __restrict__ row_start,
                            int* __restrict__ fillc, int* __restrict__ col, int E) {
    int e = blockIdx.x * 256 + threadIdx.x;
    if (e >= E) return;
    int src = ei[e], dst = ei[(size_t)E + e];
    int pos = atomicAdd(&fillc[dst], 1);
    col[row_start[dst] + pos] = src;
}

// ---- fused: gates (r,z) -> rh in LDS -> y=[xb|rh]@Wl, w=[xb|rh]@Wr ----
// One wave handles 32 nodes (2 tiles of 16); each weight fragment feeds 2 MFMAs.
__global__ __launch_bounds__(256) void fused_kernel(
    const u16* __restrict__ xb, const float* __restrict__ h,
    const u16* __restrict__ WxrT, const u16* __restrict__ WhrT,
    const u16* __restrict__ WxzT, const u16* __restrict__ WhzT,
    const u16* __restrict__ WlT,  const u16* __restrict__ WrT,
    const float* __restrict__ bxr, const float* __restrict__ bxz,
    u16* __restrict__ zo, u16* __restrict__ yo, u16* __restrict__ wo, int N)
{
    __shared__ u16 lds[4][2][16 * 128];   // per wave: 2 node-tiles, 4KB each
    const int wave = threadIdx.x >> 6;
    const int lane = threadIdx.x & 63;
    const int quad = lane >> 4;
    const int l15  = lane & 15;
    const int node0 = blockIdx.x * 128 + wave * 32;
    if (node0 >= N) return;
    u16* Lt[2] = { lds[wave][0], lds[wave][1] };

    // stage h tiles (bf16, swizzled) into LDS — coalesced f32 reads
#pragma unroll
    for (int t = 0; t < 2; t++) {
#pragma unroll
        for (int it = 0; it < 4; it++) {
            int idx = it * 64 + lane;
            int row = idx >> 4, seg = idx & 15;       // seg = 8-dim chunk
            int node = node0 + t * 16 + row; if (node >= N) node = N - 1;
            bf16x8 hv = cvt8(h + (size_t)node * D + seg * 8);
            *(bf16x8*)&Lt[t][SWZ(row, seg * 8)] = hv;
        }
    }

    // xb A-frags (global) and h A-frags (LDS) for both tiles
    bf16x8 ax[2][4], ah[2][4];
#pragma unroll
    for (int t = 0; t < 2; t++) {
        int arow = node0 + t * 16 + l15; if (arow >= N) arow = N - 1;
        const u16* xp = xb + (size_t)arow * D + quad * 8;
#pragma unroll
        for (int c = 0; c < 4; c++) {
            ax[t][c] = *(const bf16x8*)(xp + c * 32);
            ah[t][c] = *(const bf16x8*)&Lt[t][SWZ(l15, c * 32 + quad * 8)];
        }
    }

    // ---- gates phase ----
#pragma unroll
    for (int nt = 0; nt < 8; nt++) {
        f32x4 ar[2] = {{0.f,0.f,0.f,0.f},{0.f,0.f,0.f,0.f}};
        f32x4 az[2] = {{0.f,0.f,0.f,0.f},{0.f,0.f,0.f,0.f}};
        const u16* wrx = WxrT + (size_t)(nt * 16 + l15) * D + quad * 8;
        const u16* wrh = WhrT + (size_t)(nt * 16 + l15) * D + quad * 8;
        const u16* wzx = WxzT + (size_t)(nt * 16 + l15) * D + quad * 8;
        const u16* wzh = WhzT + (size_t)(nt * 16 + l15) * D + quad * 8;
#pragma unroll
        for (int c = 0; c < 4; c++) {
            bf16x8 b0 = *(const bf16x8*)(wrx + c * 32);
            bf16x8 b1 = *(const bf16x8*)(wrh + c * 32);
            bf16x8 b2 = *(const bf16x8*)(wzx + c * 32);
            bf16x8 b3 = *(const bf16x8*)(wzh + c * 32);
#pragma unroll
            for (int t = 0; t < 2; t++) {
                ar[t] = __builtin_amdgcn_mfma_f32_16x16x32_bf16(ax[t][c], b0, ar[t], 0, 0, 0);
                ar[t] = __builtin_amdgcn_mfma_f32_16x16x32_bf16(ah[t][c], b1, ar[t], 0, 0, 0);
                az[t] = __builtin_amdgcn_mfma_f32_16x16x32_bf16(ax[t][c], b2, az[t], 0, 0, 0);
                az[t] = __builtin_amdgcn_mfma_f32_16x16x32_bf16(ah[t][c], b3, az[t], 0, 0, 0);
            }
        }
        int dim = nt * 16 + l15;
        float br = bxr[dim];
        float bz = bxz[dim];
#pragma unroll
        for (int t = 0; t < 2; t++) {
#pragma unroll
            for (int reg = 0; reg < 4; reg++) {
                int row = quad * 4 + reg;
                int node = node0 + t * 16 + row;
                float hv = bf2f(Lt[t][SWZ(row, dim)]);
                float r  = sigmoidf_(ar[t][reg] + br);
                float zz = sigmoidf_(az[t][reg] + bz);
                Lt[t][SWZ(row, dim)] = f2bf(r * hv);       // rh in place of h
                if (node < N) zo[(size_t)node * D + dim] = f2bf(zz);
            }
        }
    }

    // rh A-fragments from LDS (C-layout -> A-layout transform)
    bf16x8 arh[2][4];
#pragma unroll
    for (int t = 0; t < 2; t++)
#pragma unroll
        for (int c = 0; c < 4; c++)
            arh[t][c] = *(const bf16x8*)&Lt[t][SWZ(l15, c * 32 + quad * 8)];

    // ---- proj phase: y (Wl) -> LDS (coalesced store later), w (Wr) -> scattered ----
#pragma unroll
    for (int nt = 0; nt < 8; nt++) {
        f32x4 ay[2] = {{0.f,0.f,0.f,0.f},{0.f,0.f,0.f,0.f}};
        f32x4 aw[2] = {{0.f,0.f,0.f,0.f},{0.f,0.f,0.f,0.f}};
        const u16* pl = WlT + (size_t)(nt * 16 + l15) * DC + quad * 8;
        const u16* pr = WrT + (size_t)(nt * 16 + l15) * DC + quad * 8;
#pragma unroll
        for (int c = 0; c < 4; c++) {
            bf16x8 l0 = *(const bf16x8*)(pl + c * 32);
            bf16x8 l1 = *(const bf16x8*)(pl + 128 + c * 32);
            bf16x8 r0 = *(const bf16x8*)(pr + c * 32);
            bf16x8 r1 = *(const bf16x8*)(pr + 128 + c * 32);
#pragma unroll
            for (int t = 0; t < 2; t++) {
                ay[t] = __builtin_amdgcn_mfma_f32_16x16x32_bf16(ax[t][c],  l0, ay[t], 0, 0, 0);
                ay[t] = __builtin_amdgcn_mfma_f32_16x16x32_bf16(arh[t][c], l1, ay[t], 0, 0, 0);
                aw[t] = __builtin_amdgcn_mfma_f32_16x16x32_bf16(ax[t][c],  r0, aw[t], 0, 0, 0);
                aw[t] = __builtin_amdgcn_mfma_f32_16x16x32_bf16(arh[t][c], r1, aw[t], 0, 0, 0);
            }
        }
        int dim = nt * 16 + l15;
#pragma unroll
        for (int t = 0; t < 2; t++) {
#pragma unroll
            for (int reg = 0; reg < 4; reg++) {
                int row = quad * 4 + reg;
                int node = node0 + t * 16 + row;
                Lt[t][SWZ(row, dim)] = f2bf(ay[t][reg]);   // y over rh (dead)
                if (node < N) wo[(size_t)node * D + dim] = f2bf(aw[t][reg]);
            }
        }
    }

    // store y coalesced from LDS
#pragma unroll
    for (int t = 0; t < 2; t++) {
#pragma unroll
        for (int it = 0; it < 4; it++) {
            int idx = it * 64 + lane;
            int row = idx >> 4, seg = idx & 15;
            int node = node0 + t * 16 + row;
            if (node < N)
                *(bf16x8*)(yo + (size_t)node * D + seg * 8) = *(const bf16x8*)&Lt[t][SWZ(row, seg * 8)];
        }
    }
}

// ---- pull: meanY[n] = mean over edges of y[src]  (1 wave/node, 4 edges/iter) ----
__global__ __launch_bounds__(256) void pull_kernel(
    const int* __restrict__ row_start, const int* __restrict__ deg,
    const int* __restrict__ col, const u16* __restrict__ y,
    u16* __restrict__ meanY, int N)
{
    const int wave = threadIdx.x >> 6;
    const int lane = threadIdx.x & 63;
    const int node = blockIdx.x * 4 + wave;
    if (node >= N) return;

    const int base = row_start[node];
    const int d    = deg[node];
    const int g    = lane >> 4;
    const int l15  = lane & 15;

    float a[8] = {0.f,0.f,0.f,0.f,0.f,0.f,0.f,0.f};
    for (int i = 0; i < d; i += 4) {
        int e = i + g;
        if (e < d) {
            int s = col[base + e];
            bf16x8 v = *(const bf16x8*)(y + (size_t)s * D + l15 * 8);
#pragma unroll
            for (int j = 0; j < 8; j++) a[j] += bf2f((u16)v[j]);
        }
    }
#pragma unroll
    for (int j = 0; j < 8; j++) {
        a[j] += __shfl_xor(a[j], 16, 64);
        a[j] += __shfl_xor(a[j], 32, 64);
    }
    if (lane < 16) {
        float inv = 1.0f / (float)(d > 0 ? d : 1);
        union { bf16x8 v; u16 s[8]; } o;
#pragma unroll
        for (int j = 0; j < 8; j++) o.s[j] = f2bf(a[j] * inv);
        *(bf16x8*)(meanY + (size_t)node * D + l15 * 8) = o.v;
    }
}

// out = (1-z)*(meanY + bl + w) + z*h   (pure elementwise, f32 out)
__global__ __launch_bounds__(256) void combine_kernel(
    const u16* __restrict__ z, const u16* __restrict__ w,
    const u16* __restrict__ meanY, const float* __restrict__ h,
    const float* __restrict__ bl, float* __restrict__ out, long long total)
{
    long long g = ((long long)blockIdx.x * 256 + threadIdx.x) * 4;
    if (g >= total) return;
    int dim = (int)(g & (D - 1));
    s16x4 zv = *(const s16x4*)(z + g);
    s16x4 wv = *(const s16x4*)(w + g);
    s16x4 mv = *(const s16x4*)(meanY + g);
    f32x4 hv = *(const f32x4*)(h + g);
    f32x4 bv = *(const f32x4*)(bl + dim);
    f32x4 o;
#pragma unroll
    for (int j = 0; j < 4; j++) {
        float zz = bf2f((u16)zv[j]);
        float nv = bf2f((u16)mv[j]) + bv[j] + bf2f((u16)wv[j]);
        o[j] = (1.0f - zz) * nv + zz * hv[j];
    }
    *(f32x4*)(out + g) = o;
}

extern "C" void kernel_launch(void* const* d_in, const int* in_sizes, int n_in,
                              void* d_out, int out_size, void* d_ws, size_t ws_size,
                              hipStream_t stream)
{
    const float* x   = (const float*)d_in[0];
    const int*   ei  = (const int*)d_in[1];
    const float* h   = (const float*)d_in[2];
    const float* Wxr = (const float*)d_in[3];
    const float* bxr = (const float*)d_in[4];
    const float* Whr = (const float*)d_in[5];
    const float* Wxz = (const float*)d_in[6];
    const float* bxz = (const float*)d_in[7];
    const float* Whz = (const float*)d_in[8];
    const float* Wl  = (const float*)d_in[9];
    const float* bl  = (const float*)d_in[10];
    const float* Wr  = (const float*)d_in[11];
    float* out = (float*)d_out;

    const int N = in_sizes[0] / D;
    const int E = in_sizes[1] / 2;
    if (N <= 0 || E <= 0) return;

    const int nbn = (N + 255) / 256;
    if (nbn > 256) return;                  // scan2 capacity; N=50000 ok

    char* ws = (char*)d_ws;
    size_t off = 0;
    auto alloc = [&](size_t bytes) -> void* {
        void* p = ws + off;
        off += (bytes + 255) & ~(size_t)255;
        return p;
    };
    u16*   z     = (u16*)  alloc((size_t)N * D * 2);
    u16*   xbuf  = (u16*)  alloc((size_t)N * D * 2);
    u16*   y     = (u16*)  alloc((size_t)N * D * 2);
    u16*   w     = (u16*)  alloc((size_t)N * D * 2);
    u16*   meanY = (u16*)  alloc((size_t)N * D * 2);
    int*   deg   = (int*)  alloc((size_t)N * 4);
    int*   rstart= (int*)  alloc((size_t)N * 4);
    int*   fillc = (int*)  alloc((size_t)N * 4);
    int*   bsum  = (int*)  alloc((size_t)256 * 4);
    int*   col   = (int*)  alloc((size_t)E * 4);
    u16*   WxrT  = (u16*)  alloc((size_t)D * D * 2);
    u16*   WhrT  = (u16*)  alloc((size_t)D * D * 2);
    u16*   WxzT  = (u16*)  alloc((size_t)D * D * 2);
    u16*   WhzT  = (u16*)  alloc((size_t)D * D * 2);
    u16*   WlT   = (u16*)  alloc((size_t)DC * D * 2);
    u16*   WrT   = (u16*)  alloc((size_t)DC * D * 2);
    (void)n_in; (void)out_size;
    if (off > ws_size) return;   // clean failure instead of OOB fault

    hipMemsetAsync(deg, 0, (size_t)N * 4, stream);

    const int nbx = (N * D + 255) / 256;
    const int nbh = (E + 255) / 256;
    prep_kernel<<<512 + nbx + nbh, 256, 0, stream>>>(
        Wxr, Whr, Wxz, Whz, Wl, Wr,
        WxrT, WhrT, WxzT, WhzT, WlT, WrT,
        x, xbuf, ei, deg, N, E, nbx);

    scan1_kernel<<<nbn, 256, 0, stream>>>(deg, rstart, bsum, N);
    scan2_kernel<<<1, 256, 0, stream>>>(bsum, nbn);
    scan3_kernel<<<nbn, 256, 0, stream>>>(rstart, bsum, fillc, N);
    fill_kernel<<<nbh, 256, 0, stream>>>(ei, rstart, fillc, col, E);

    fused_kernel<<<(N + 127) / 128, 256, 0, stream>>>(
        xbuf, h, WxrT, WhrT, WxzT, WhzT, WlT, WrT, bxr, bxz, z, y, w, N);

    pull_kernel<<<(N + 3) / 4, 256, 0, stream>>>(rstart, deg, col, y, meanY, N);

    long long total = (long long)N * D;
    combine_kernel<<<(int)((total / 4 + 255) / 256), 256, 0, stream>>>(
        z, w, meanY, h, bl, out, total);
}